// Round 8
// baseline (570.721 us; speedup 1.0000x reference)
//
#include <hip/hip_runtime.h>
#include <cstdint>

using half_t = _Float16;
using half8  = __attribute__((ext_vector_type(8))) _Float16;
using half4v = __attribute__((ext_vector_type(4))) _Float16;
using f32x4  = __attribute__((ext_vector_type(4))) float;
using flt4v  = __attribute__((ext_vector_type(4))) float;

namespace {
constexpr int kT = 16, kH = 1024, kFH = 4096, kC = 2513, kCP = 2560;
constexpr int kSlot = 128 * 1024;   // elements per state slot (128 rows x 1024)
constexpr int kPar  = 17 * kSlot;   // elements per parity plane
}

__device__ __forceinline__ void gload16(const void* g, void* l) {
  __builtin_amdgcn_global_load_lds((const __attribute__((address_space(1))) void*)g,
                                   (__attribute__((address_space(3))) void*)l, 16, 0, 0);
}
__device__ __forceinline__ float sgm(float x) { return 1.0f / (1.0f + __expf(-x)); }

// ---------------- fused setup: weight casts + x transpose + bias packs -------
__global__ void setup_all(const flt4v* __restrict__ WiR, const flt4v* __restrict__ WhR,
                          const flt4v* __restrict__ WiU, const flt4v* __restrict__ WhU,
                          const flt4v* __restrict__ Wc, const float* __restrict__ x,
                          const float* __restrict__ biR, const float* __restrict__ bhR,
                          const float* __restrict__ biU, const float* __restrict__ bhU,
                          const float* __restrict__ bc,
                          half4v* __restrict__ WiRh, half4v* __restrict__ WhRh,
                          half4v* __restrict__ WiUh, half4v* __restrict__ WhUh,
                          half4v* __restrict__ Wch, half_t* __restrict__ xh,
                          float* __restrict__ br_p, float* __restrict__ bu_p,
                          float* __restrict__ bcp) {
  int blk = blockIdx.x;
  if (blk < 18944) {  // weight casts, 1024 f32 elements (256 x flt4v) per block
    long i = (long)blk * 256 + threadIdx.x;
    const long Q = 1048576;
    if (i < Q) { WiRh[i] = __builtin_convertvector(WiR[i], half4v); return; }
    i -= Q;
    if (i < Q) { WhRh[i] = __builtin_convertvector(WhR[i], half4v); return; }
    i -= Q;
    if (i < Q) { WiUh[i] = __builtin_convertvector(WiU[i], half4v); return; }
    i -= Q;
    if (i < Q) { WhUh[i] = __builtin_convertvector(WhU[i], half4v); return; }
    i -= Q;
    if (i < (long)kC * kH / 4) {
      Wch[i] = __builtin_convertvector(Wc[i], half4v);
    } else if (i < (long)kCP * kH / 4) {
      half4v z = {(_Float16)0, (_Float16)0, (_Float16)0, (_Float16)0};
      Wch[i] = z;
    }
    return;
  }
  blk -= 18944;
  if (blk < 2048) {  // x transpose [B,T,F] -> [t*128+b][F], fp16
    int t = blk >> 7, b = blk & 127;
    const flt4v* src = (const flt4v*)(x + ((long)b * kT + t) * kH);
    half4v* dst = (half4v*)(xh + (long)blk * kH);
    dst[threadIdx.x] = __builtin_convertvector(src[threadIdx.x], half4v);
    return;
  }
  blk -= 2048;
  {  // bias packs: br_p/bu_p [j][gate]; bcp padded linear
    int i = blk * 256 + threadIdx.x;
    if (i < kFH) {
      int j = i >> 2, gt = i & 3;
      br_p[i] = biR[gt * kH + j] + bhR[gt * kH + j];
      bu_p[i] = biU[gt * kH + j] + bhU[gt * kH + j];
    }
    if (i < kCP) bcp[i] = (i < kC) ? bc[i] : 0.0f;
  }
}

// gate-interleaved B-row mapping: LDS B-row r -> weight row gate(r)*1024 + j0 + jj(r)
__device__ __forceinline__ int brow_gate(int r, int j0) {
  return (((r >> 4) & 3) << 10) + j0 + ((r >> 6) << 4) + (r & 15);
}

// ---------------- GEMM core: MR x 128 tile, K=1024, BK=32, dbuf + swizzle ----
// LDS per buffer: [rows][4 slots of 8 halfs]; slot s holds global k-chunk
// (s ^ ((row>>1)&3)). Row stride = 64 B so bank = (row&1)*16 + slot*4; the
// (row>>1) XOR key spreads rows 0,2,4,6 across 4 slots -> 2-way (free, m136).
// LDS: A 2*MR*32, B 2*128*32 halfs = 24 KiB at MR=64 -> 4 blocks/CU.
template <int MR>
__device__ __forceinline__ void gemm_core(
    const half_t* __restrict__ A, const half_t* __restrict__ B,
    const long* ao, const long* bo, half_t* AsB, half_t* BsB,
    int tid, int wm, int wc, int row16, int g, f32x4 acc[][4]) {
  constexpr int UA = MR / 64;       // A stage instrs (4 KB each)
  constexpr int ABUF = MR * 32;     // halfs per A buffer
#pragma unroll
  for (int i = 0; i < UA; ++i) gload16(A + ao[i], AsB + (i * 256 + tid) * 8);
#pragma unroll
  for (int i = 0; i < 2; ++i) gload16(B + bo[i], BsB + (i * 256 + tid) * 8);
  __syncthreads();
  int p = 0;
  for (int kt = 32; kt <= 1024; kt += 32) {
    if (kt < 1024) {
      half_t* as_n = AsB + (p ^ 1) * ABUF;
      half_t* bs_n = BsB + (p ^ 1) * 4096;
#pragma unroll
      for (int i = 0; i < UA; ++i) gload16(A + ao[i] + kt, as_n + (i * 256 + tid) * 8);
#pragma unroll
      for (int i = 0; i < 2; ++i) gload16(B + bo[i] + kt, bs_n + (i * 256 + tid) * 8);
    }
    const half_t* as_ = AsB + p * ABUF;
    const half_t* bs_ = BsB + p * 4096;
    half8 af[MR / 32], bf[4];
#pragma unroll
    for (int a = 0; a < MR / 32; ++a) {
      const int row = wm * (MR / 2) + (a << 4) + row16;
      const int slot = g ^ ((row >> 1) & 3);
      af[a] = *(const half8*)&as_[row * 32 + slot * 8];
    }
#pragma unroll
    for (int b = 0; b < 4; ++b) {
      const int row = (wc << 6) + (b << 4) + row16;
      const int slot = g ^ ((row >> 1) & 3);
      bf[b] = *(const half8*)&bs_[row * 32 + slot * 8];
    }
#pragma unroll
    for (int a = 0; a < MR / 32; ++a)
#pragma unroll
      for (int b = 0; b < 4; ++b)
        acc[a][b] = __builtin_amdgcn_mfma_f32_16x16x32_f16(af[a], bf[b], acc[a][b], 0, 0, 0);
    __syncthreads();
    p ^= 1;
  }
}

// ---------------- pipelined recurrence step + folded proj segments -----------
// Global step u. blockIdx.y = 2*seg + mhalf (MR=64 half-tiles).
// Segments seg < nRec: recurrence (roll if u<=16 && seg==0, else chain c).
// Chains read parity (u&1)^1, write u&1. Roll at u reads slot u-2, seeds slot
// u-1. Finals land in parity-0 slots 0..15 (= cls input).
// Segments seg >= nRec: proj tiles, p = projBase + (seg - nRec):
//   p=0:(xiR,r0) p=1:(xiU,r0) p in 2..16:(xiR,r p-1) p>=17:(xiU,r p-16)
__global__ __launch_bounds__(256, 4) void pipe_step(
    const int u, const int nRec, const int projBase,
    const half_t* __restrict__ xh,
    const half_t* __restrict__ WiRh, const half_t* __restrict__ WiUh,
    const float* __restrict__ brp, const float* __restrict__ bup,
    const half_t* __restrict__ Wr, const half_t* __restrict__ Wu,
    half_t* __restrict__ xiR, half_t* __restrict__ xiU,
    half_t* __restrict__ Hbuf, float* __restrict__ Cbuf) {
  constexpr int MR = 64, FA = 2;
  __shared__ __align__(16) half_t As[2 * MR * 32];
  __shared__ __align__(16) half_t Bs[2 * 128 * 32];
  const int tid = threadIdx.x;
  const int lane = tid & 63;
  const int w = tid >> 6, wm = w >> 1, wc = w & 1;
  const int row16 = lane & 15;
  const int g = lane >> 4;
  const int j0 = blockIdx.x << 5;   // j-tile; XCD = blockIdx.x%8 (32*y % 8 == 0)
  const int sy = blockIdx.y;
  const int seg = sy >> 1;
  const int mrow0 = (sy & 1) << 6;

  f32x4 acc[FA][4];
  const f32x4 z4 = {0.f, 0.f, 0.f, 0.f};
#pragma unroll
  for (int a = 0; a < FA; ++a)
#pragma unroll
    for (int b = 0; b < 4; ++b) acc[a][b] = z4;

  // staging: thread covers LDS row sr (+64 for 2nd B instr), pre-swizzled kk
  const int sr = tid >> 2;
  const int kk = ((tid & 3) ^ ((sr >> 1) & 3)) * 8;

  if (seg < nRec) {
    const bool isRoll = (u <= 16) && (seg == 0);
    const int c = (u <= 16) ? (seg - 1) : seg;
    const int pr = (u & 1) ^ 1, pw = u & 1;
    const int slot_in_raw = isRoll ? (u - 2) : c;
    const bool zeroA = (slot_in_raw < 0);
    const int slot_in = zeroA ? 0 : slot_in_raw;
    const int slot_out = isRoll ? (u - 1) : c;
    const half_t* A  = Hbuf + (size_t)pr * kPar + (size_t)slot_in * kSlot;
    const float* Cin = Cbuf + (size_t)pr * kPar + (size_t)slot_in * kSlot;
    half_t* Ho = Hbuf + (size_t)pw * kPar + (size_t)slot_out * kSlot;
    float*  Co = Cbuf + (size_t)pw * kPar + (size_t)slot_out * kSlot;
    const half_t* W  = isRoll ? Wr : Wu;
    const half_t* xi = isRoll ? (xiR + (size_t)(u - 1) * 524288)
                              : (xiU + (size_t)c * 524288);

    if (!zeroA) {
      long ao[1], bo[2];
      ao[0] = (long)(mrow0 + sr) * kH + kk;
      bo[0] = (long)brow_gate(sr, j0) * kH + kk;
      bo[1] = (long)brow_gate(sr + 64, j0) * kH + kk;
      gemm_core<MR>(A, W, ao, bo, As, Bs, tid, wm, wc, row16, g, acc);
    }

    const int jg = j0 + (wc << 4) + row16;
#pragma unroll
    for (int a = 0; a < FA; ++a) {
      const int mb = mrow0 + wm * (MR / 2) + (a << 4) + (g << 2);
#pragma unroll
      for (int r = 0; r < 4; ++r) {
        const int m = mb + r;
        const half4v xv = *(const half4v*)&xi[((long)m * kH + jg) * 4];
        const float pi = acc[a][0][r] + (float)xv[0];
        const float pf = acc[a][1][r] + (float)xv[1];
        const float pg = acc[a][2][r] + (float)xv[2];
        const float po = acc[a][3][r] + (float)xv[3];
        const float co = zeroA ? 0.0f : Cin[(long)m * kH + jg];
        const float cn = sgm(pf) * co + sgm(pi) * tanhf(pg);
        const float hn = sgm(po) * tanhf(cn);
        Ho[(long)m * kH + jg] = (half_t)hn;
        Co[(long)m * kH + jg] = cn;
      }
    }
  } else {
    // ---- folded input-projection tile ----
    const int p = projBase + (seg - nRec);
    int z, rr;
    if (p == 0)       { z = 0; rr = 0; }
    else if (p == 1)  { z = 1; rr = 0; }
    else if (p <= 16) { z = 0; rr = p - 1; }
    else              { z = 1; rr = p - 16; }
    const half_t* Wt = z ? WiUh : WiRh;
    const float* bias_p = z ? bup : brp;
    half_t* xi = z ? xiU : xiR;
    const int m0 = (rr << 7) + mrow0;

    long ao[1], bo[2];
    ao[0] = (long)(m0 + sr) * kH + kk;
    bo[0] = (long)brow_gate(sr, j0) * kH + kk;
    bo[1] = (long)brow_gate(sr + 64, j0) * kH + kk;
    gemm_core<MR>(xh, Wt, ao, bo, As, Bs, tid, wm, wc, row16, g, acc);

    const int jg = j0 + (wc << 4) + row16;
    const f32x4 bv = *(const f32x4*)&bias_p[jg * 4];
#pragma unroll
    for (int a = 0; a < FA; ++a) {
      const int mb = m0 + wm * (MR / 2) + (a << 4) + (g << 2);
#pragma unroll
      for (int r4 = 0; r4 < 4; ++r4) {
        half4v o;
        o[0] = (half_t)(acc[a][0][r4] + bv[0]);
        o[1] = (half_t)(acc[a][1][r4] + bv[1]);
        o[2] = (half_t)(acc[a][2][r4] + bv[2]);
        o[3] = (half_t)(acc[a][3][r4] + bv[3]);
        *(half4v*)&xi[((long)(mb + r4) * kH + jg) * 4] = o;
      }
    }
  }
}

// ---------------- classifier: half-tiles; A = parity-0 plane of Hbuf ---------
__global__ __launch_bounds__(256, 4) void cls_gemm(
    const half_t* __restrict__ Hfin, const half_t* __restrict__ Wcw,
    const float* __restrict__ bcp, float* __restrict__ out) {
  __shared__ __align__(16) half_t As[2 * 64 * 32];
  __shared__ __align__(16) half_t Bs[2 * 128 * 32];
  const int tid = threadIdx.x;
  const int lane = tid & 63;
  const int w = tid >> 6, wm = w >> 1, wc = w & 1;
  const int row16 = lane & 15;
  const int g = lane >> 4;
  const int n00 = blockIdx.x << 7;
  const int t = blockIdx.y >> 1;
  const int m0 = (t << 7) + ((blockIdx.y & 1) << 6);

  const int sr = tid >> 2;
  const int kk = ((tid & 3) ^ ((sr >> 1) & 3)) * 8;
  long ao[1], bo[2];
  ao[0] = (long)(m0 + sr) * kH + kk;
  bo[0] = (long)(n00 + sr) * kH + kk;
  bo[1] = (long)(n00 + sr + 64) * kH + kk;

  f32x4 acc[2][4];
  const f32x4 z4 = {0.f, 0.f, 0.f, 0.f};
#pragma unroll
  for (int a = 0; a < 2; ++a)
#pragma unroll
    for (int b = 0; b < 4; ++b) acc[a][b] = z4;

  gemm_core<64>(Hfin, Wcw, ao, bo, As, Bs, tid, wm, wc, row16, g, acc);

#pragma unroll
  for (int a = 0; a < 2; ++a) {
    const int mb = m0 + wm * 32 + (a << 4) + (g << 2);
#pragma unroll
    for (int b = 0; b < 4; ++b) {
      const int n = n00 + (wc << 6) + (b << 4) + row16;
      if (n < kC) {
        const float bvv = bcp[n];
#pragma unroll
        for (int r = 0; r < 4; ++r) {
          const int m = mb + r;
          const int bi = m & 127;
          out[((long)bi * kT + t) * kC + n] = acc[a][b][r] + bvv;
        }
      }
    }
  }
}

extern "C" void kernel_launch(void* const* d_in, const int* in_sizes, int n_in,
                              void* d_out, int out_size, void* d_ws, size_t ws_size,
                              hipStream_t stream) {
  const float* x   = (const float*)d_in[0];
  const float* WiR = (const float*)d_in[1];
  const float* WhR = (const float*)d_in[2];
  const float* biR = (const float*)d_in[3];
  const float* bhR = (const float*)d_in[4];
  const float* WiU = (const float*)d_in[5];
  const float* WhU = (const float*)d_in[6];
  const float* biU = (const float*)d_in[7];
  const float* bhU = (const float*)d_in[8];
  const float* Wc  = (const float*)d_in[9];
  const float* bc  = (const float*)d_in[10];

  size_t off = 0;
  auto alloc = [&](size_t bytes) -> void* {
    void* p = (char*)d_ws + off;
    off += (bytes + 255) & ~(size_t)255;
    return p;
  };
  half_t* xh   = (half_t*)alloc((size_t)2048 * 1024 * 2);
  half_t* WiRh = (half_t*)alloc((size_t)4096 * 1024 * 2);
  half_t* WhRh = (half_t*)alloc((size_t)4096 * 1024 * 2);
  half_t* WiUh = (half_t*)alloc((size_t)4096 * 1024 * 2);
  half_t* WhUh = (half_t*)alloc((size_t)4096 * 1024 * 2);
  half_t* Wch  = (half_t*)alloc((size_t)2560 * 1024 * 2);
  float*  br   = (float*)alloc(4096 * 4);
  float*  bu   = (float*)alloc(4096 * 4);
  float*  bcp  = (float*)alloc(2560 * 4);
  half_t* xiR  = (half_t*)alloc((size_t)2048 * 4096 * 2);
  half_t* xiU  = (half_t*)alloc((size_t)2048 * 4096 * 2);
  half_t* Hbuf = (half_t*)alloc((size_t)2 * kPar * 2);
  float*  Cbuf = (float*)alloc((size_t)2 * kPar * 4);
  float*  outp = (float*)d_out;
  (void)ws_size; (void)in_sizes; (void)n_in; (void)out_size;

  // setup: weight casts + x transpose + bias packs (one dispatch)
  setup_all<<<21008, 256, 0, stream>>>(
      (const flt4v*)WiR, (const flt4v*)WhR, (const flt4v*)WiU, (const flt4v*)WhU,
      (const flt4v*)Wc, x, biR, bhR, biU, bhU, bc,
      (half4v*)WiRh, (half4v*)WhRh, (half4v*)WiUh, (half4v*)WhUh, (half4v*)Wch,
      xh, br, bu, bcp);

  // P0: proj p=0..2 (xiR r0, xiU r0, xiR r1) as 6 half-tiles — seeds u=1,2
  pipe_step<<<dim3(32, 6), 256, 0, stream>>>(
      0, 0, 0, xh, WiRh, WiUh, br, bu, WhRh, WhUh, xiR, xiU, Hbuf, Cbuf);

  // pipelined recurrences; proj folded into early steps:
  //  u=1: p=3..13 (xiR r2..12), u=2: p=14..23 (xiR r13..15 + xiU r1..7),
  //  u=3: p=24..31 (xiU r8..15). All deps land >=1 dispatch before first read.
  for (int u = 1; u <= 18; ++u) {
    const int nchain = (u >= 2) ? ((u - 2 < 15 ? u - 2 : 15) + 1) : 0;
    const int nRec = (u <= 16 ? 1 : 0) + nchain;
    int projBase = 0, nProj = 0;
    if (u == 1) { projBase = 3;  nProj = 11; }
    if (u == 2) { projBase = 14; nProj = 10; }
    if (u == 3) { projBase = 24; nProj = 8;  }
    pipe_step<<<dim3(32, 2 * (nRec + nProj)), 256, 0, stream>>>(
        u, nRec, projBase, xh, WiRh, WiUh, br, bu, WhRh, WhUh, xiR, xiU,
        Hbuf, Cbuf);
  }

  // classifier: finals are parity-0 slots 0..15; half-tiles (20 x 32 grid)
  cls_gemm<<<dim3(20, 32), 256, 0, stream>>>(Hbuf, Wch, bcp, (float*)outp);
}

// Round 9
// 483.457 us; speedup vs baseline: 1.1805x; 1.1805x over previous
//
#include <hip/hip_runtime.h>
#include <cstdint>

using half_t = _Float16;
using half8  = __attribute__((ext_vector_type(8))) _Float16;
using half4v = __attribute__((ext_vector_type(4))) _Float16;
using f32x4  = __attribute__((ext_vector_type(4))) float;
using flt4v  = __attribute__((ext_vector_type(4))) float;

namespace {
constexpr int kT = 16, kH = 1024, kFH = 4096, kC = 2513, kCP = 2560;
constexpr int kSlot = 128 * 1024;   // elements per state slot (128 rows x 1024)
constexpr int kPar  = 17 * kSlot;   // elements per parity plane
}

__device__ __forceinline__ void gload16(const void* g, void* l) {
  __builtin_amdgcn_global_load_lds((const __attribute__((address_space(1))) void*)g,
                                   (__attribute__((address_space(3))) void*)l, 16, 0, 0);
}
__device__ __forceinline__ float sgm(float x) { return 1.0f / (1.0f + __expf(-x)); }

// ---------------- fused setup: weight casts + x transpose + bias packs -------
__global__ void setup_all(const flt4v* __restrict__ WiR, const flt4v* __restrict__ WhR,
                          const flt4v* __restrict__ WiU, const flt4v* __restrict__ WhU,
                          const flt4v* __restrict__ Wc, const float* __restrict__ x,
                          const float* __restrict__ biR, const float* __restrict__ bhR,
                          const float* __restrict__ biU, const float* __restrict__ bhU,
                          const float* __restrict__ bc,
                          half4v* __restrict__ WiRh, half4v* __restrict__ WhRh,
                          half4v* __restrict__ WiUh, half4v* __restrict__ WhUh,
                          half4v* __restrict__ Wch, half_t* __restrict__ xh,
                          float* __restrict__ br_p, float* __restrict__ bu_p,
                          float* __restrict__ bcp) {
  int blk = blockIdx.x;
  if (blk < 18944) {  // weight casts, 1024 f32 elements (256 x flt4v) per block
    long i = (long)blk * 256 + threadIdx.x;
    const long Q = 1048576;
    if (i < Q) { WiRh[i] = __builtin_convertvector(WiR[i], half4v); return; }
    i -= Q;
    if (i < Q) { WhRh[i] = __builtin_convertvector(WhR[i], half4v); return; }
    i -= Q;
    if (i < Q) { WiUh[i] = __builtin_convertvector(WiU[i], half4v); return; }
    i -= Q;
    if (i < Q) { WhUh[i] = __builtin_convertvector(WhU[i], half4v); return; }
    i -= Q;
    if (i < (long)kC * kH / 4) {
      Wch[i] = __builtin_convertvector(Wc[i], half4v);
    } else if (i < (long)kCP * kH / 4) {
      half4v z = {(_Float16)0, (_Float16)0, (_Float16)0, (_Float16)0};
      Wch[i] = z;
    }
    return;
  }
  blk -= 18944;
  if (blk < 2048) {  // x transpose [B,T,F] -> [t*128+b][F], fp16
    int t = blk >> 7, b = blk & 127;
    const flt4v* src = (const flt4v*)(x + ((long)b * kT + t) * kH);
    half4v* dst = (half4v*)(xh + (long)blk * kH);
    dst[threadIdx.x] = __builtin_convertvector(src[threadIdx.x], half4v);
    return;
  }
  blk -= 2048;
  {  // bias packs: br_p/bu_p [j][gate]; bcp padded linear
    int i = blk * 256 + threadIdx.x;
    if (i < kFH) {
      int j = i >> 2, gt = i & 3;
      br_p[i] = biR[gt * kH + j] + bhR[gt * kH + j];
      bu_p[i] = biU[gt * kH + j] + bhU[gt * kH + j];
    }
    if (i < kCP) bcp[i] = (i < kC) ? bc[i] : 0.0f;
  }
}

// gate-interleaved B-row mapping: LDS B-row r -> weight row gate(r)*1024 + j0 + jj(r)
__device__ __forceinline__ int brow_gate(int r, int j0) {
  return (((r >> 4) & 3) << 10) + j0 + ((r >> 6) << 4) + (r & 15);
}

// ---------------- GEMM core: MR x 128 tile, K=1024, BK=64, dbuf + swizzle ----
// (round-3/7 proven core, templated on M rows: 128 = full, 64 = half-tile.)
// LDS per buffer: [MR rows][8 slots of 8 halfs]; slot s holds global k-chunk
// (s ^ (row&7)) -> ds_read_b128 2-way-conflict-free (free per m136).
template <int MR>
__device__ __forceinline__ void gemm_core(
    const half_t* __restrict__ A, const half_t* __restrict__ B,
    const long* ao, const long* bo, half_t* AsB, half_t* BsB,
    int tid, int wm, int wc, int row16, int g, f32x4 acc[][4]) {
  constexpr int UA = MR / 32;       // A stage iterations per thread
  constexpr int ABUF = MR * 64;     // halfs per A buffer
#pragma unroll
  for (int i = 0; i < UA; ++i) gload16(A + ao[i], AsB + (i * 256 + tid) * 8);
#pragma unroll
  for (int i = 0; i < 4; ++i) gload16(B + bo[i], BsB + (i * 256 + tid) * 8);
  __syncthreads();
  int p = 0;
  for (int kt = 64; kt <= 1024; kt += 64) {
    if (kt < 1024) {
      half_t* as_n = AsB + (p ^ 1) * ABUF;
      half_t* bs_n = BsB + (p ^ 1) * 8192;
#pragma unroll
      for (int i = 0; i < UA; ++i) gload16(A + ao[i] + kt, as_n + (i * 256 + tid) * 8);
#pragma unroll
      for (int i = 0; i < 4; ++i) gload16(B + bo[i] + kt, bs_n + (i * 256 + tid) * 8);
    }
    const half_t* as_ = AsB + p * ABUF;
    const half_t* bs_ = BsB + p * 8192;
#pragma unroll
    for (int s = 0; s < 2; ++s) {
      half8 af[UA], bf[4];
#pragma unroll
      for (int a = 0; a < UA; ++a) {
        const int row = wm * (MR / 2) + (a << 4) + row16;
        const int slot = (s * 4 + g) ^ (row & 7);
        af[a] = *(const half8*)&as_[row * 64 + slot * 8];
      }
#pragma unroll
      for (int b = 0; b < 4; ++b) {
        const int row = (wc << 6) + (b << 4) + row16;
        const int slot = (s * 4 + g) ^ (row & 7);
        bf[b] = *(const half8*)&bs_[row * 64 + slot * 8];
      }
#pragma unroll
      for (int a = 0; a < UA; ++a)
#pragma unroll
        for (int b = 0; b < 4; ++b)
          acc[a][b] = __builtin_amdgcn_mfma_f32_16x16x32_f16(af[a], bf[b], acc[a][b], 0, 0, 0);
    }
    __syncthreads();
    p ^= 1;
  }
}

// ---------------- pipelined recurrence step + folded proj segments -----------
// Global step u. MR=64: blockIdx.y = 2*seg + mhalf; MR=128: blockIdx.y = seg.
// Segments seg < nRec: recurrence (roll if u<=16 && seg==0, else chain c).
// Chains read parity (u&1)^1, write u&1. Roll at u reads slot u-2, seeds slot
// u-1. Finals land in parity-0 slots 0..15 (= cls input).
// Segments seg >= nRec: proj tiles, p = projBase + (seg - nRec):
//   p=0:(xiR,r0) p=1:(xiU,r0) p in 2..16:(xiR,r p-1) p>=17:(xiU,r p-16)
// Special: p==0 ALSO computes roll step 1 (h0=c0=0 -> gates from xi only) and
// writes Hbuf/Cbuf slot 0 parity 1 — this replaces the former u=1 dispatch.
template <int MR>
__global__ __launch_bounds__(256, (MR == 64 ? 3 : 2)) void pipe_step(
    const int u, const int nRec, const int projBase,
    const half_t* __restrict__ xh,
    const half_t* __restrict__ WiRh, const half_t* __restrict__ WiUh,
    const float* __restrict__ brp, const float* __restrict__ bup,
    const half_t* __restrict__ Wr, const half_t* __restrict__ Wu,
    half_t* __restrict__ xiR, half_t* __restrict__ xiU,
    half_t* __restrict__ Hbuf, float* __restrict__ Cbuf) {
  __shared__ __align__(16) half_t As[2 * MR * 64];
  __shared__ __align__(16) half_t Bs[2 * 8192];
  constexpr int FA = MR / 32;       // A fragments per wave
  const int tid = threadIdx.x;
  const int lane = tid & 63;
  const int w = tid >> 6, wm = w >> 1, wc = w & 1;
  const int row16 = lane & 15;
  const int g = lane >> 4;
  const int j0 = blockIdx.x << 5;   // j-tile; XCD = blockIdx.x%8 (32*y % 8 == 0)
  const int sy = blockIdx.y;
  const int seg = (MR == 64) ? (sy >> 1) : sy;
  const int mrow0 = (MR == 64) ? ((sy & 1) << 6) : 0;

  f32x4 acc[FA][4];
  const f32x4 z4 = {0.f, 0.f, 0.f, 0.f};
#pragma unroll
  for (int a = 0; a < FA; ++a)
#pragma unroll
    for (int b = 0; b < 4; ++b) acc[a][b] = z4;

  // staging rows/offsets (LDS-local row; kk pre-swizzled k-offset)
  int srow[4], skk[4];
#pragma unroll
  for (int i = 0; i < 4; ++i) {
    srow[i] = i * 32 + (tid >> 3);
    skk[i] = ((tid & 7) ^ (srow[i] & 7)) * 8;
  }

  if (seg < nRec) {
    const bool isRoll = (u <= 16) && (seg == 0);
    const int c = (u <= 16) ? (seg - 1) : seg;
    const int pr = (u & 1) ^ 1, pw = u & 1;
    const int slot_in = isRoll ? (u - 2) : c;
    const int slot_out = isRoll ? (u - 1) : c;
    const half_t* A  = Hbuf + (size_t)pr * kPar + (size_t)slot_in * kSlot;
    const float* Cin = Cbuf + (size_t)pr * kPar + (size_t)slot_in * kSlot;
    half_t* Ho = Hbuf + (size_t)pw * kPar + (size_t)slot_out * kSlot;
    float*  Co = Cbuf + (size_t)pw * kPar + (size_t)slot_out * kSlot;
    const half_t* W  = isRoll ? Wr : Wu;
    const half_t* xi = isRoll ? (xiR + (size_t)(u - 1) * 524288)
                              : (xiU + (size_t)c * 524288);

    long ao[FA], bo[4];
#pragma unroll
    for (int i = 0; i < FA; ++i) ao[i] = (long)(mrow0 + srow[i]) * kH + skk[i];
#pragma unroll
    for (int i = 0; i < 4; ++i) bo[i] = (long)brow_gate(srow[i], j0) * kH + skk[i];
    gemm_core<MR>(A, W, ao, bo, As, Bs, tid, wm, wc, row16, g, acc);

    const int jg = j0 + (wc << 4) + row16;
#pragma unroll
    for (int a = 0; a < FA; ++a) {
      const int mb = mrow0 + wm * (MR / 2) + (a << 4) + (g << 2);
#pragma unroll
      for (int r = 0; r < 4; ++r) {
        const int m = mb + r;
        const half4v xv = *(const half4v*)&xi[((long)m * kH + jg) * 4];
        const float pi = acc[a][0][r] + (float)xv[0];
        const float pf = acc[a][1][r] + (float)xv[1];
        const float pg = acc[a][2][r] + (float)xv[2];
        const float po = acc[a][3][r] + (float)xv[3];
        const float co = Cin[(long)m * kH + jg];
        const float cn = sgm(pf) * co + sgm(pi) * tanhf(pg);
        const float hn = sgm(po) * tanhf(cn);
        Ho[(long)m * kH + jg] = (half_t)hn;
        Co[(long)m * kH + jg] = cn;
      }
    }
  } else {
    // ---- folded input-projection tile ----
    const int p = projBase + (seg - nRec);
    int z, rr;
    if (p == 0)       { z = 0; rr = 0; }
    else if (p == 1)  { z = 1; rr = 0; }
    else if (p <= 16) { z = 0; rr = p - 1; }
    else              { z = 1; rr = p - 16; }
    const half_t* Wt = z ? WiUh : WiRh;
    const float* bias_p = z ? bup : brp;
    half_t* xi = z ? xiU : xiR;
    const int m0 = (rr << 7) + mrow0;

    long ao[FA], bo[4];
#pragma unroll
    for (int i = 0; i < FA; ++i) ao[i] = (long)(m0 + srow[i]) * kH + skk[i];
#pragma unroll
    for (int i = 0; i < 4; ++i) bo[i] = (long)brow_gate(srow[i], j0) * kH + skk[i];
    gemm_core<MR>(xh, Wt, ao, bo, As, Bs, tid, wm, wc, row16, g, acc);

    const int jg = j0 + (wc << 4) + row16;
    const f32x4 bv = *(const f32x4*)&bias_p[jg * 4];
#pragma unroll
    for (int a = 0; a < FA; ++a) {
      const int mb = m0 + wm * (MR / 2) + (a << 4) + (g << 2);
#pragma unroll
      for (int r4 = 0; r4 < 4; ++r4) {
        const float pi = acc[a][0][r4] + bv[0];
        const float pf = acc[a][1][r4] + bv[1];
        const float pg = acc[a][2][r4] + bv[2];
        const float po = acc[a][3][r4] + bv[3];
        half4v o;
        o[0] = (half_t)pi; o[1] = (half_t)pf; o[2] = (half_t)pg; o[3] = (half_t)po;
        *(half4v*)&xi[((long)(mb + r4) * kH + jg) * 4] = o;
        if (p == 0) {  // roll step 1 fold: c=0, h=0
          const float cn = sgm(pi) * tanhf(pg);
          const float hn = sgm(po) * tanhf(cn);
          Hbuf[(size_t)kPar + (long)(mb + r4) * kH + jg] = (half_t)hn;
          Cbuf[(size_t)kPar + (long)(mb + r4) * kH + jg] = cn;
        }
      }
    }
  }
}

// ---------------- classifier: half-tiles; A = parity-0 plane of Hbuf ---------
__global__ __launch_bounds__(256, 3) void cls_gemm(
    const half_t* __restrict__ Hfin, const half_t* __restrict__ Wcw,
    const float* __restrict__ bcp, float* __restrict__ out) {
  __shared__ __align__(16) half_t As[2 * 4096];
  __shared__ __align__(16) half_t Bs[2 * 8192];
  const int tid = threadIdx.x;
  const int lane = tid & 63;
  const int w = tid >> 6, wm = w >> 1, wc = w & 1;
  const int row16 = lane & 15;
  const int g = lane >> 4;
  const int n00 = blockIdx.x << 7;
  const int t = blockIdx.y >> 1;
  const int m0 = (t << 7) + ((blockIdx.y & 1) << 6);

  int srow[4], skk[4];
#pragma unroll
  for (int i = 0; i < 4; ++i) {
    srow[i] = i * 32 + (tid >> 3);
    skk[i] = ((tid & 7) ^ (srow[i] & 7)) * 8;
  }
  long ao[2], bo[4];
#pragma unroll
  for (int i = 0; i < 2; ++i) ao[i] = (long)(m0 + srow[i]) * kH + skk[i];
#pragma unroll
  for (int i = 0; i < 4; ++i) bo[i] = (long)(n00 + srow[i]) * kH + skk[i];

  f32x4 acc[2][4];
  const f32x4 z4 = {0.f, 0.f, 0.f, 0.f};
#pragma unroll
  for (int a = 0; a < 2; ++a)
#pragma unroll
    for (int b = 0; b < 4; ++b) acc[a][b] = z4;

  gemm_core<64>(Hfin, Wcw, ao, bo, As, Bs, tid, wm, wc, row16, g, acc);

#pragma unroll
  for (int a = 0; a < 2; ++a) {
    const int mb = m0 + wm * 32 + (a << 4) + (g << 2);
#pragma unroll
    for (int b = 0; b < 4; ++b) {
      const int n = n00 + (wc << 6) + (b << 4) + row16;
      if (n < kC) {
        const float bvv = bcp[n];
#pragma unroll
        for (int r = 0; r < 4; ++r) {
          const int m = mb + r;
          const int bi = m & 127;
          out[((long)bi * kT + t) * kC + n] = acc[a][b][r] + bvv;
        }
      }
    }
  }
}

extern "C" void kernel_launch(void* const* d_in, const int* in_sizes, int n_in,
                              void* d_out, int out_size, void* d_ws, size_t ws_size,
                              hipStream_t stream) {
  const float* x   = (const float*)d_in[0];
  const float* WiR = (const float*)d_in[1];
  const float* WhR = (const float*)d_in[2];
  const float* biR = (const float*)d_in[3];
  const float* bhR = (const float*)d_in[4];
  const float* WiU = (const float*)d_in[5];
  const float* WhU = (const float*)d_in[6];
  const float* biU = (const float*)d_in[7];
  const float* bhU = (const float*)d_in[8];
  const float* Wc  = (const float*)d_in[9];
  const float* bc  = (const float*)d_in[10];

  size_t off = 0;
  auto alloc = [&](size_t bytes) -> void* {
    void* p = (char*)d_ws + off;
    off += (bytes + 255) & ~(size_t)255;
    return p;
  };
  half_t* xh   = (half_t*)alloc((size_t)2048 * 1024 * 2);
  half_t* WiRh = (half_t*)alloc((size_t)4096 * 1024 * 2);
  half_t* WhRh = (half_t*)alloc((size_t)4096 * 1024 * 2);
  half_t* WiUh = (half_t*)alloc((size_t)4096 * 1024 * 2);
  half_t* WhUh = (half_t*)alloc((size_t)4096 * 1024 * 2);
  half_t* Wch  = (half_t*)alloc((size_t)2560 * 1024 * 2);
  float*  br   = (float*)alloc(4096 * 4);
  float*  bu   = (float*)alloc(4096 * 4);
  float*  bcp  = (float*)alloc(2560 * 4);
  half_t* xiR  = (half_t*)alloc((size_t)2048 * 4096 * 2);
  half_t* xiU  = (half_t*)alloc((size_t)2048 * 4096 * 2);
  half_t* Hbuf = (half_t*)alloc((size_t)2 * kPar * 2);
  float*  Cbuf = (float*)alloc((size_t)2 * kPar * 4);
  float*  outp = (float*)d_out;
  (void)ws_size; (void)in_sizes; (void)n_in; (void)out_size;

  // setup: weight casts + x transpose + bias packs (one dispatch)
  setup_all<<<21008, 256, 0, stream>>>(
      (const flt4v*)WiR, (const flt4v*)WhR, (const flt4v*)WiU, (const flt4v*)WhU,
      (const flt4v*)Wc, x, biR, bhR, biU, bhU, bc,
      (half4v*)WiRh, (half4v*)WhRh, (half4v*)WiUh, (half4v*)WhUh, (half4v*)Wch,
      xh, br, bu, bcp);

  // P0: proj p=0..13 (xiR r0..12 + xiU r0) as 28 half-tiles; p=0 also folds
  // roll step 1 (writes Hbuf/Cbuf slot 0 parity 1) — replaces the u=1 dispatch
  pipe_step<64><<<dim3(32, 28), 256, 0, stream>>>(
      0, 0, 0, xh, WiRh, WiUh, br, bu, WhRh, WhUh, xiR, xiU, Hbuf, Cbuf);

  // pipelined recurrences, u = 2..18; remaining proj folded into u=2,3:
  //  u=2: p=14..23 (xiR r13..15 + xiU r1..7), u=3: p=24..31 (xiU r8..15).
  //  All deps land >=1 dispatch before first read.
  for (int u = 2; u <= 18; ++u) {
    const int nchain = (u - 2 < 15 ? u - 2 : 15) + 1;
    const int nRec = (u <= 16 ? 1 : 0) + nchain;
    int projBase = 0, nProj = 0;
    if (u == 2) { projBase = 14; nProj = 10; }
    if (u == 3) { projBase = 24; nProj = 8;  }
    if (u <= 12) {
      pipe_step<64><<<dim3(32, 2 * (nRec + nProj)), 256, 0, stream>>>(
          u, nRec, projBase, xh, WiRh, WiUh, br, bu, WhRh, WhUh, xiR, xiU,
          Hbuf, Cbuf);
    } else {
      pipe_step<128><<<dim3(32, nRec), 256, 0, stream>>>(
          u, nRec, 0, xh, WiRh, WiUh, br, bu, WhRh, WhUh, xiR, xiU,
          Hbuf, Cbuf);
    }
  }

  // classifier: finals are parity-0 slots 0..15; half-tiles (20 x 32 grid)
  cls_gemm<<<dim3(20, 32), 256, 0, stream>>>(Hbuf, Wch, bcp, (float*)outp);
}

// Round 10
// 475.316 us; speedup vs baseline: 1.2007x; 1.0171x over previous
//
#include <hip/hip_runtime.h>
#include <cstdint>

using half_t = _Float16;
using half8  = __attribute__((ext_vector_type(8))) _Float16;
using half4v = __attribute__((ext_vector_type(4))) _Float16;
using f32x4  = __attribute__((ext_vector_type(4))) float;
using flt4v  = __attribute__((ext_vector_type(4))) float;

namespace {
constexpr int kT = 16, kH = 1024, kFH = 4096, kC = 2513, kCP = 2560;
constexpr int kSlot = 128 * 1024;   // elements per state slot (128 rows x 1024)
constexpr int kPar  = 17 * kSlot;   // elements per parity plane
}

// proj sequence: global slot s -> (z, row). Scheduled so every xi row lands
// >=1 dispatch before its first reader (see launcher comments).
__device__ __constant__ unsigned char g_seq_z[32] = {
    0,0,1,0, 0,0,1,1, 0,0,1,1, 0,0,1,1, 0,0,1, 0,0,1, 0,0,1, 0,1,1, 1,1, 1,1};
__device__ __constant__ unsigned char g_seq_r[32] = {
    0,1,0,2, 3,4,1,2, 5,6,3,4, 7,8,5,6, 9,10,7, 11,12,8, 13,14,9, 15,10,11, 12,13, 14,15};

__device__ __forceinline__ void gload16(const void* g, void* l) {
  __builtin_amdgcn_global_load_lds((const __attribute__((address_space(1))) void*)g,
                                   (__attribute__((address_space(3))) void*)l, 16, 0, 0);
}
__device__ __forceinline__ float sgm(float x) { return 1.0f / (1.0f + __expf(-x)); }

// ---------------- slim setup: x transpose + WiR/WiU casts + bias packs -------
__global__ void setup_all(const flt4v* __restrict__ WiR, const flt4v* __restrict__ WiU,
                          const float* __restrict__ x,
                          const float* __restrict__ biR, const float* __restrict__ bhR,
                          const float* __restrict__ biU, const float* __restrict__ bhU,
                          const float* __restrict__ bc,
                          half4v* __restrict__ WiRh, half4v* __restrict__ WiUh,
                          half_t* __restrict__ xh,
                          float* __restrict__ br_p, float* __restrict__ bu_p,
                          float* __restrict__ bcp) {
  int blk = blockIdx.x;
  if (blk < 8192) {  // WiR/WiU casts
    long i = (long)blk * 256 + threadIdx.x;
    const long Q = 1048576;
    if (i < Q) { WiRh[i] = __builtin_convertvector(WiR[i], half4v); return; }
    i -= Q;
    WiUh[i] = __builtin_convertvector(WiU[i], half4v);
    return;
  }
  blk -= 8192;
  if (blk < 2048) {  // x transpose [B,T,F] -> [t*128+b][F], fp16
    int t = blk >> 7, b = blk & 127;
    const flt4v* src = (const flt4v*)(x + ((long)b * kT + t) * kH);
    half4v* dst = (half4v*)(xh + (long)blk * kH);
    dst[threadIdx.x] = __builtin_convertvector(src[threadIdx.x], half4v);
    return;
  }
  blk -= 2048;
  {  // bias packs: br_p/bu_p [j][gate]; bcp padded linear
    int i = blk * 256 + threadIdx.x;
    if (i < kFH) {
      int j = i >> 2, gt = i & 3;
      br_p[i] = biR[gt * kH + j] + bhR[gt * kH + j];
      bu_p[i] = biU[gt * kH + j] + bhU[gt * kH + j];
    }
    if (i < kCP) bcp[i] = (i < kC) ? bc[i] : 0.0f;
  }
}

// gate-interleaved B-row mapping: LDS B-row r -> weight row gate(r)*1024 + j0 + jj(r)
__device__ __forceinline__ int brow_gate(int r, int j0) {
  return (((r >> 4) & 3) << 10) + j0 + ((r >> 6) << 4) + (r & 15);
}

// ---------------- GEMM core: MR x 128 tile, K=1024, BK=64, dbuf + swizzle ----
// (round-3/7 proven core, templated on M rows: 128 = full, 64 = half-tile.)
// LDS per buffer: [MR rows][8 slots of 8 halfs]; slot s holds global k-chunk
// (s ^ (row&7)) -> ds_read_b128 2-way-conflict-free (free per m136).
template <int MR>
__device__ __forceinline__ void gemm_core(
    const half_t* __restrict__ A, const half_t* __restrict__ B,
    const long* ao, const long* bo, half_t* AsB, half_t* BsB,
    int tid, int wm, int wc, int row16, int g, f32x4 acc[][4]) {
  constexpr int UA = MR / 32;       // A stage iterations per thread
  constexpr int ABUF = MR * 64;     // halfs per A buffer
#pragma unroll
  for (int i = 0; i < UA; ++i) gload16(A + ao[i], AsB + (i * 256 + tid) * 8);
#pragma unroll
  for (int i = 0; i < 4; ++i) gload16(B + bo[i], BsB + (i * 256 + tid) * 8);
  __syncthreads();
  int p = 0;
  for (int kt = 64; kt <= 1024; kt += 64) {
    if (kt < 1024) {
      half_t* as_n = AsB + (p ^ 1) * ABUF;
      half_t* bs_n = BsB + (p ^ 1) * 8192;
#pragma unroll
      for (int i = 0; i < UA; ++i) gload16(A + ao[i] + kt, as_n + (i * 256 + tid) * 8);
#pragma unroll
      for (int i = 0; i < 4; ++i) gload16(B + bo[i] + kt, bs_n + (i * 256 + tid) * 8);
    }
    const half_t* as_ = AsB + p * ABUF;
    const half_t* bs_ = BsB + p * 8192;
#pragma unroll
    for (int s = 0; s < 2; ++s) {
      half8 af[UA], bf[4];
#pragma unroll
      for (int a = 0; a < UA; ++a) {
        const int row = wm * (MR / 2) + (a << 4) + row16;
        const int slot = (s * 4 + g) ^ (row & 7);
        af[a] = *(const half8*)&as_[row * 64 + slot * 8];
      }
#pragma unroll
      for (int b = 0; b < 4; ++b) {
        const int row = (wc << 6) + (b << 4) + row16;
        const int slot = (s * 4 + g) ^ (row & 7);
        bf[b] = *(const half8*)&bs_[row * 64 + slot * 8];
      }
#pragma unroll
      for (int a = 0; a < UA; ++a)
#pragma unroll
        for (int b = 0; b < 4; ++b)
          acc[a][b] = __builtin_amdgcn_mfma_f32_16x16x32_f16(af[a], bf[b], acc[a][b], 0, 0, 0);
    }
    __syncthreads();
    p ^= 1;
  }
}

// ---------------- pipelined recurrence step + folded proj/cast segments ------
// Global step u. MR=64: blockIdx.y = 2*seg + mhalf; MR=128: blockIdx.y = seg.
// seg < nRec: recurrence (roll if u<=16 && seg==0, else chain c). Chains read
// parity (u&1)^1, write u&1. Roll at u reads slot u-2, seeds slot u-1. Finals
// land in parity-0 slots 0..15 (= cls input).
// seg in [nRec, nRec+nProj): proj tile s = projStart + (seg-nRec), mapped via
// g_seq_z/r. s==0 ALSO computes roll step 1 (h0=c0=0) into slot 0 parity 1.
// blockIdx.y >= 2*(nRec+nProj) (P0 only): grid-stride weight-cast blocks for
// WhR/WhU/Wc (deferred from setup; first needed at u=2 / cls).
template <int MR>
__global__ __launch_bounds__(256, (MR == 64 ? 3 : 2)) void pipe_step(
    const int u, const int nRec, const int projStart, const int nProj,
    const half_t* __restrict__ xh,
    const half_t* __restrict__ WiRh, const half_t* __restrict__ WiUh,
    const float* __restrict__ brp, const float* __restrict__ bup,
    const half_t* __restrict__ Wr, const half_t* __restrict__ Wu,
    half_t* __restrict__ xiR, half_t* __restrict__ xiU,
    half_t* __restrict__ Hbuf, float* __restrict__ Cbuf,
    const flt4v* __restrict__ WhRf, const flt4v* __restrict__ WhUf,
    const flt4v* __restrict__ Wcf,
    half4v* __restrict__ WhRhD, half4v* __restrict__ WhUhD,
    half4v* __restrict__ WchD) {
  __shared__ __align__(16) half_t As[2 * MR * 64];
  __shared__ __align__(16) half_t Bs[2 * 8192];
  constexpr int FA = MR / 32;       // A fragments per wave
  const int tid = threadIdx.x;
  const int lane = tid & 63;
  const int w = tid >> 6, wm = w >> 1, wc = w & 1;
  const int row16 = lane & 15;
  const int g = lane >> 4;
  const int j0 = blockIdx.x << 5;   // j-tile; XCD = blockIdx.x%8 (32*y % 8 == 0)
  const int sy = blockIdx.y;
  const int seg = (MR == 64) ? (sy >> 1) : sy;
  const int mrow0 = (MR == 64) ? ((sy & 1) << 6) : 0;
  const int nTot = nRec + nProj;

  if (MR == 64 && sy >= 2 * nTot) {
    // ---- weight-cast block (P0 only): WhR | WhU | Wc-pad, grid-stride ----
    const long TCB = (long)(gridDim.y - 2 * nTot) * 32;
    const long fc = (long)(sy - 2 * nTot) * 32 + blockIdx.x;
    const long Q = 1048576, total = 2 * Q + (long)kCP * kH / 4;
    const half4v z4h = {(_Float16)0, (_Float16)0, (_Float16)0, (_Float16)0};
    for (long i = fc * 256 + tid; i < total; i += TCB * 256) {
      if (i < Q) {
        WhRhD[i] = __builtin_convertvector(WhRf[i], half4v);
      } else if (i < 2 * Q) {
        WhUhD[i - Q] = __builtin_convertvector(WhUf[i - Q], half4v);
      } else {
        const long k = i - 2 * Q;
        WchD[k] = (k < (long)kC * kH / 4)
                      ? __builtin_convertvector(Wcf[k], half4v) : z4h;
      }
    }
    return;
  }

  f32x4 acc[FA][4];
  const f32x4 z4 = {0.f, 0.f, 0.f, 0.f};
#pragma unroll
  for (int a = 0; a < FA; ++a)
#pragma unroll
    for (int b = 0; b < 4; ++b) acc[a][b] = z4;

  // staging rows/offsets (LDS-local row; kk pre-swizzled k-offset)
  int srow[4], skk[4];
#pragma unroll
  for (int i = 0; i < 4; ++i) {
    srow[i] = i * 32 + (tid >> 3);
    skk[i] = ((tid & 7) ^ (srow[i] & 7)) * 8;
  }

  if (seg < nRec) {
    const bool isRoll = (u <= 16) && (seg == 0);
    const int c = (u <= 16) ? (seg - 1) : seg;
    const int pr = (u & 1) ^ 1, pw = u & 1;
    const int slot_in = isRoll ? (u - 2) : c;
    const int slot_out = isRoll ? (u - 1) : c;
    const half_t* A  = Hbuf + (size_t)pr * kPar + (size_t)slot_in * kSlot;
    const float* Cin = Cbuf + (size_t)pr * kPar + (size_t)slot_in * kSlot;
    half_t* Ho = Hbuf + (size_t)pw * kPar + (size_t)slot_out * kSlot;
    float*  Co = Cbuf + (size_t)pw * kPar + (size_t)slot_out * kSlot;
    const half_t* W  = isRoll ? Wr : Wu;
    const half_t* xi = isRoll ? (xiR + (size_t)(u - 1) * 524288)
                              : (xiU + (size_t)c * 524288);

    long ao[FA], bo[4];
#pragma unroll
    for (int i = 0; i < FA; ++i) ao[i] = (long)(mrow0 + srow[i]) * kH + skk[i];
#pragma unroll
    for (int i = 0; i < 4; ++i) bo[i] = (long)brow_gate(srow[i], j0) * kH + skk[i];
    gemm_core<MR>(A, W, ao, bo, As, Bs, tid, wm, wc, row16, g, acc);

    const int jg = j0 + (wc << 4) + row16;
#pragma unroll
    for (int a = 0; a < FA; ++a) {
      const int mb = mrow0 + wm * (MR / 2) + (a << 4) + (g << 2);
#pragma unroll
      for (int r = 0; r < 4; ++r) {
        const int m = mb + r;
        const half4v xv = *(const half4v*)&xi[((long)m * kH + jg) * 4];
        const float pi = acc[a][0][r] + (float)xv[0];
        const float pf = acc[a][1][r] + (float)xv[1];
        const float pg = acc[a][2][r] + (float)xv[2];
        const float po = acc[a][3][r] + (float)xv[3];
        const float co = Cin[(long)m * kH + jg];
        const float cn = sgm(pf) * co + sgm(pi) * tanhf(pg);
        const float hn = sgm(po) * tanhf(cn);
        Ho[(long)m * kH + jg] = (half_t)hn;
        Co[(long)m * kH + jg] = cn;
      }
    }
  } else {
    // ---- folded input-projection tile ----
    const int s = projStart + (seg - nRec);
    const int z = g_seq_z[s];
    const int rr = g_seq_r[s];
    const half_t* Wt = z ? WiUh : WiRh;
    const float* bias_p = z ? bup : brp;
    half_t* xi = z ? xiU : xiR;
    const int m0 = (rr << 7) + mrow0;

    long ao[FA], bo[4];
#pragma unroll
    for (int i = 0; i < FA; ++i) ao[i] = (long)(m0 + srow[i]) * kH + skk[i];
#pragma unroll
    for (int i = 0; i < 4; ++i) bo[i] = (long)brow_gate(srow[i], j0) * kH + skk[i];
    gemm_core<MR>(xh, Wt, ao, bo, As, Bs, tid, wm, wc, row16, g, acc);

    const int jg = j0 + (wc << 4) + row16;
    const f32x4 bv = *(const f32x4*)&bias_p[jg * 4];
#pragma unroll
    for (int a = 0; a < FA; ++a) {
      const int mb = m0 + wm * (MR / 2) + (a << 4) + (g << 2);
#pragma unroll
      for (int r4 = 0; r4 < 4; ++r4) {
        const float pi = acc[a][0][r4] + bv[0];
        const float pf = acc[a][1][r4] + bv[1];
        const float pg = acc[a][2][r4] + bv[2];
        const float po = acc[a][3][r4] + bv[3];
        half4v o;
        o[0] = (half_t)pi; o[1] = (half_t)pf; o[2] = (half_t)pg; o[3] = (half_t)po;
        *(half4v*)&xi[((long)(mb + r4) * kH + jg) * 4] = o;
        if (s == 0) {  // roll step 1 fold: c=0, h=0 -> slot 0 parity 1
          const float cn = sgm(pi) * tanhf(pg);
          const float hn = sgm(po) * tanhf(cn);
          Hbuf[(size_t)kPar + (long)(mb + r4) * kH + jg] = (half_t)hn;
          Cbuf[(size_t)kPar + (long)(mb + r4) * kH + jg] = cn;
        }
      }
    }
  }
}

// ---------------- classifier: half-tiles; A = parity-0 plane of Hbuf ---------
__global__ __launch_bounds__(256, 3) void cls_gemm(
    const half_t* __restrict__ Hfin, const half_t* __restrict__ Wcw,
    const float* __restrict__ bcp, float* __restrict__ out) {
  __shared__ __align__(16) half_t As[2 * 4096];
  __shared__ __align__(16) half_t Bs[2 * 8192];
  const int tid = threadIdx.x;
  const int lane = tid & 63;
  const int w = tid >> 6, wm = w >> 1, wc = w & 1;
  const int row16 = lane & 15;
  const int g = lane >> 4;
  const int n00 = blockIdx.x << 7;
  const int t = blockIdx.y >> 1;
  const int m0 = (t << 7) + ((blockIdx.y & 1) << 6);

  int srow[4], skk[4];
#pragma unroll
  for (int i = 0; i < 4; ++i) {
    srow[i] = i * 32 + (tid >> 3);
    skk[i] = ((tid & 7) ^ (srow[i] & 7)) * 8;
  }
  long ao[2], bo[4];
#pragma unroll
  for (int i = 0; i < 2; ++i) ao[i] = (long)(m0 + srow[i]) * kH + skk[i];
#pragma unroll
  for (int i = 0; i < 4; ++i) bo[i] = (long)(n00 + srow[i]) * kH + skk[i];

  f32x4 acc[2][4];
  const f32x4 z4 = {0.f, 0.f, 0.f, 0.f};
#pragma unroll
  for (int a = 0; a < 2; ++a)
#pragma unroll
    for (int b = 0; b < 4; ++b) acc[a][b] = z4;

  gemm_core<64>(Hfin, Wcw, ao, bo, As, Bs, tid, wm, wc, row16, g, acc);

#pragma unroll
  for (int a = 0; a < 2; ++a) {
    const int mb = m0 + wm * 32 + (a << 4) + (g << 2);
#pragma unroll
    for (int b = 0; b < 4; ++b) {
      const int n = n00 + (wc << 6) + (b << 4) + row16;
      if (n < kC) {
        const float bvv = bcp[n];
#pragma unroll
        for (int r = 0; r < 4; ++r) {
          const int m = mb + r;
          const int bi = m & 127;
          out[((long)bi * kT + t) * kC + n] = acc[a][b][r] + bvv;
        }
      }
    }
  }
}

extern "C" void kernel_launch(void* const* d_in, const int* in_sizes, int n_in,
                              void* d_out, int out_size, void* d_ws, size_t ws_size,
                              hipStream_t stream) {
  const float* x   = (const float*)d_in[0];
  const float* WiR = (const float*)d_in[1];
  const float* WhR = (const float*)d_in[2];
  const float* biR = (const float*)d_in[3];
  const float* bhR = (const float*)d_in[4];
  const float* WiU = (const float*)d_in[5];
  const float* WhU = (const float*)d_in[6];
  const float* biU = (const float*)d_in[7];
  const float* bhU = (const float*)d_in[8];
  const float* Wc  = (const float*)d_in[9];
  const float* bc  = (const float*)d_in[10];

  size_t off = 0;
  auto alloc = [&](size_t bytes) -> void* {
    void* p = (char*)d_ws + off;
    off += (bytes + 255) & ~(size_t)255;
    return p;
  };
  half_t* xh   = (half_t*)alloc((size_t)2048 * 1024 * 2);
  half_t* WiRh = (half_t*)alloc((size_t)4096 * 1024 * 2);
  half_t* WhRh = (half_t*)alloc((size_t)4096 * 1024 * 2);
  half_t* WiUh = (half_t*)alloc((size_t)4096 * 1024 * 2);
  half_t* WhUh = (half_t*)alloc((size_t)4096 * 1024 * 2);
  half_t* Wch  = (half_t*)alloc((size_t)2560 * 1024 * 2);
  float*  br   = (float*)alloc(4096 * 4);
  float*  bu   = (float*)alloc(4096 * 4);
  float*  bcp  = (float*)alloc(2560 * 4);
  half_t* xiR  = (half_t*)alloc((size_t)2048 * 4096 * 2);
  half_t* xiU  = (half_t*)alloc((size_t)2048 * 4096 * 2);
  half_t* Hbuf = (half_t*)alloc((size_t)2 * kPar * 2);
  float*  Cbuf = (float*)alloc((size_t)2 * kPar * 4);
  float*  outp = (float*)d_out;
  (void)ws_size; (void)in_sizes; (void)n_in; (void)out_size;

  // slim setup: x transpose + WiR/WiU casts + bias packs (one dispatch)
  setup_all<<<10256, 256, 0, stream>>>(
      (const flt4v*)WiR, (const flt4v*)WiU, x, biR, bhR, biU, bhU, bc,
      (half4v*)WiRh, (half4v*)WiUh, xh, br, bu, bcp);

  // P0: proj s=0..3 (xiR r0[+roll1 fold], r1; xiU r0; xiR r2) as 8 half-tiles
  // + 16 y of grid-stride cast blocks (WhR/WhU/Wc -> fp16; needed from u=2).
  pipe_step<64><<<dim3(32, 2 * 4 + 16), 256, 0, stream>>>(
      0, 0, 0, 4, xh, WiRh, WiUh, br, bu, WhRh, WhUh, xiR, xiU, Hbuf, Cbuf,
      (const flt4v*)WhR, (const flt4v*)WhU, (const flt4v*)Wc,
      (half4v*)WhRh, (half4v*)WhUh, (half4v*)Wch);

  // pipelined recurrences, u=2..18; remaining proj spread over the
  // latency-bound small steps (u=2..10) per g_seq schedule. Every xi row
  // lands >=1 dispatch before its first reader (verified row-by-row).
  static const int pjs[19] = {0,0, 4, 8, 12, 16, 19, 22, 25, 28, 30, 0,0,0,0,0,0,0,0};
  static const int pjn[19] = {0,0, 4, 4,  4,  3,  3,  3,  3,  2,  2, 0,0,0,0,0,0,0,0};
  for (int u = 2; u <= 18; ++u) {
    const int nchain = (u - 2 < 15 ? u - 2 : 15) + 1;
    const int nRec = (u <= 16 ? 1 : 0) + nchain;
    const int nProj = pjn[u];
    if (u <= 12) {
      pipe_step<64><<<dim3(32, 2 * (nRec + nProj)), 256, 0, stream>>>(
          u, nRec, pjs[u], nProj, xh, WiRh, WiUh, br, bu, WhRh, WhUh, xiR, xiU,
          Hbuf, Cbuf, (const flt4v*)WhR, (const flt4v*)WhU, (const flt4v*)Wc,
          (half4v*)WhRh, (half4v*)WhUh, (half4v*)Wch);
    } else {
      pipe_step<128><<<dim3(32, nRec), 256, 0, stream>>>(
          u, nRec, 0, 0, xh, WiRh, WiUh, br, bu, WhRh, WhUh, xiR, xiU,
          Hbuf, Cbuf, (const flt4v*)WhR, (const flt4v*)WhU, (const flt4v*)Wc,
          (half4v*)WhRh, (half4v*)WhUh, (half4v*)Wch);
    }
  }

  // classifier: finals are parity-0 slots 0..15; half-tiles (20 x 32 grid)
  cls_gemm<<<dim3(20, 32), 256, 0, stream>>>(Hbuf, Wch, bcp, (float*)outp);
}

// Round 11
// 425.192 us; speedup vs baseline: 1.3423x; 1.1179x over previous
//
#include <hip/hip_runtime.h>
#include <cstdint>

using half_t = _Float16;
using half8  = __attribute__((ext_vector_type(8))) _Float16;
using half4v = __attribute__((ext_vector_type(4))) _Float16;
using f32x4  = __attribute__((ext_vector_type(4))) float;
using flt4v  = __attribute__((ext_vector_type(4))) float;

namespace {
constexpr int kT = 16, kH = 1024, kFH = 4096, kC = 2513, kCP = 2560;
constexpr int kSlot = 128 * 1024;   // elements per state slot (128 rows x 1024)
constexpr int kPar  = 17 * kSlot;   // elements per parity plane
}

// proj sequence: global slot s -> (z, row). Scheduled so every xi row lands
// >=1 dispatch before its first reader (see launcher comments).
__device__ __constant__ unsigned char g_seq_z[32] = {
    0,0,1,0, 0,0,1,1, 0,0,1,1, 0,0,1,1, 0,0,1, 0,0,1, 0,0,1, 0,1,1, 1,1, 1,1};
__device__ __constant__ unsigned char g_seq_r[32] = {
    0,1,0,2, 3,4,1,2, 5,6,3,4, 7,8,5,6, 9,10,7, 11,12,8, 13,14,9, 15,10,11, 12,13, 14,15};

__device__ __forceinline__ void gload16(const void* g, void* l) {
  __builtin_amdgcn_global_load_lds((const __attribute__((address_space(1))) void*)g,
                                   (__attribute__((address_space(3))) void*)l, 16, 0, 0);
}
// fast sigmoid / tanh: __expf + v_rcp (1-ulp class); clamp keeps exp finite.
__device__ __forceinline__ float sgm(float x) {
  return __builtin_amdgcn_rcpf(1.0f + __expf(-x));
}
__device__ __forceinline__ float ftanh(float x) {
  x = fminf(9.0f, fmaxf(-9.0f, x));
  return 1.0f - 2.0f * __builtin_amdgcn_rcpf(1.0f + __expf(2.0f * x));
}

// ---------------- slim setup: x transpose + WiR/WiU casts + bias packs -------
__global__ void setup_all(const flt4v* __restrict__ WiR, const flt4v* __restrict__ WiU,
                          const float* __restrict__ x,
                          const float* __restrict__ biR, const float* __restrict__ bhR,
                          const float* __restrict__ biU, const float* __restrict__ bhU,
                          const float* __restrict__ bc,
                          half4v* __restrict__ WiRh, half4v* __restrict__ WiUh,
                          half_t* __restrict__ xh,
                          float* __restrict__ br_p, float* __restrict__ bu_p,
                          float* __restrict__ bcp) {
  int blk = blockIdx.x;
  if (blk < 8192) {  // WiR/WiU casts
    long i = (long)blk * 256 + threadIdx.x;
    const long Q = 1048576;
    if (i < Q) { WiRh[i] = __builtin_convertvector(WiR[i], half4v); return; }
    i -= Q;
    WiUh[i] = __builtin_convertvector(WiU[i], half4v);
    return;
  }
  blk -= 8192;
  if (blk < 2048) {  // x transpose [B,T,F] -> [t*128+b][F], fp16
    int t = blk >> 7, b = blk & 127;
    const flt4v* src = (const flt4v*)(x + ((long)b * kT + t) * kH);
    half4v* dst = (half4v*)(xh + (long)blk * kH);
    dst[threadIdx.x] = __builtin_convertvector(src[threadIdx.x], half4v);
    return;
  }
  blk -= 2048;
  {  // bias packs: br_p/bu_p [j][gate]; bcp padded linear
    int i = blk * 256 + threadIdx.x;
    if (i < kFH) {
      int j = i >> 2, gt = i & 3;
      br_p[i] = biR[gt * kH + j] + bhR[gt * kH + j];
      bu_p[i] = biU[gt * kH + j] + bhU[gt * kH + j];
    }
    if (i < kCP) bcp[i] = (i < kC) ? bc[i] : 0.0f;
  }
}

// gate-interleaved B-row mapping: LDS B-row r -> weight row gate(r)*1024 + j0 + jj(r)
__device__ __forceinline__ int brow_gate(int r, int j0) {
  return (((r >> 4) & 3) << 10) + j0 + ((r >> 6) << 4) + (r & 15);
}

// ---------------- GEMM core: MR x 128 tile, K=1024, BK=64, dbuf + swizzle ----
// (round-3/7 proven core, templated on M rows: 128 = full, 64 = half-tile.)
// LDS per buffer: [MR rows][8 slots of 8 halfs]; slot s holds global k-chunk
// (s ^ (row&7)) -> ds_read_b128 2-way-conflict-free (free per m136).
template <int MR>
__device__ __forceinline__ void gemm_core(
    const half_t* __restrict__ A, const half_t* __restrict__ B,
    const long* ao, const long* bo, half_t* AsB, half_t* BsB,
    int tid, int wm, int wc, int row16, int g, f32x4 acc[][4]) {
  constexpr int UA = MR / 32;       // A stage iterations per thread
  constexpr int ABUF = MR * 64;     // halfs per A buffer
#pragma unroll
  for (int i = 0; i < UA; ++i) gload16(A + ao[i], AsB + (i * 256 + tid) * 8);
#pragma unroll
  for (int i = 0; i < 4; ++i) gload16(B + bo[i], BsB + (i * 256 + tid) * 8);
  __syncthreads();
  int p = 0;
  for (int kt = 64; kt <= 1024; kt += 64) {
    if (kt < 1024) {
      half_t* as_n = AsB + (p ^ 1) * ABUF;
      half_t* bs_n = BsB + (p ^ 1) * 8192;
#pragma unroll
      for (int i = 0; i < UA; ++i) gload16(A + ao[i] + kt, as_n + (i * 256 + tid) * 8);
#pragma unroll
      for (int i = 0; i < 4; ++i) gload16(B + bo[i] + kt, bs_n + (i * 256 + tid) * 8);
    }
    const half_t* as_ = AsB + p * ABUF;
    const half_t* bs_ = BsB + p * 8192;
#pragma unroll
    for (int s = 0; s < 2; ++s) {
      half8 af[UA], bf[4];
#pragma unroll
      for (int a = 0; a < UA; ++a) {
        const int row = wm * (MR / 2) + (a << 4) + row16;
        const int slot = (s * 4 + g) ^ (row & 7);
        af[a] = *(const half8*)&as_[row * 64 + slot * 8];
      }
#pragma unroll
      for (int b = 0; b < 4; ++b) {
        const int row = (wc << 6) + (b << 4) + row16;
        const int slot = (s * 4 + g) ^ (row & 7);
        bf[b] = *(const half8*)&bs_[row * 64 + slot * 8];
      }
#pragma unroll
      for (int a = 0; a < UA; ++a)
#pragma unroll
        for (int b = 0; b < 4; ++b)
          acc[a][b] = __builtin_amdgcn_mfma_f32_16x16x32_f16(af[a], bf[b], acc[a][b], 0, 0, 0);
    }
    __syncthreads();
    p ^= 1;
  }
}

// ---------------- pipelined recurrence step + folded proj/cast segments ------
// Global step u. MR=64: blockIdx.y = 2*seg + mhalf; MR=128: blockIdx.y = seg.
// seg < nRec: recurrence (roll if u<=16 && seg==0, else chain c). Chains read
// parity (u&1)^1, write u&1. Roll at u reads slot u-2, seeds slot u-1. Finals
// land in parity-0 slots 0..15 (= cls input).
// seg in [nRec, nRec+nProj): proj tile s = projStart + (seg-nRec), mapped via
// g_seq_z/r. s==0 ALSO computes roll step 1 (h0=c0=0) into slot 0 parity 1.
// blockIdx.y >= 2*(nRec+nProj) (P0 only): grid-stride weight-cast blocks for
// WhR/WhU/Wc (deferred from setup; first needed at u=2 / cls).
template <int MR>
__global__ __launch_bounds__(256, (MR == 64 ? 3 : 2)) void pipe_step(
    const int u, const int nRec, const int projStart, const int nProj,
    const half_t* __restrict__ xh,
    const half_t* __restrict__ WiRh, const half_t* __restrict__ WiUh,
    const float* __restrict__ brp, const float* __restrict__ bup,
    const half_t* __restrict__ Wr, const half_t* __restrict__ Wu,
    half_t* __restrict__ xiR, half_t* __restrict__ xiU,
    half_t* __restrict__ Hbuf, float* __restrict__ Cbuf,
    const flt4v* __restrict__ WhRf, const flt4v* __restrict__ WhUf,
    const flt4v* __restrict__ Wcf,
    half4v* __restrict__ WhRhD, half4v* __restrict__ WhUhD,
    half4v* __restrict__ WchD) {
  __shared__ __align__(16) half_t As[2 * MR * 64];
  __shared__ __align__(16) half_t Bs[2 * 8192];
  constexpr int FA = MR / 32;       // A fragments per wave
  const int tid = threadIdx.x;
  const int lane = tid & 63;
  const int w = tid >> 6, wm = w >> 1, wc = w & 1;
  const int row16 = lane & 15;
  const int g = lane >> 4;
  const int j0 = blockIdx.x << 5;   // j-tile; XCD = blockIdx.x%8 (32*y % 8 == 0)
  const int sy = blockIdx.y;
  const int seg = (MR == 64) ? (sy >> 1) : sy;
  const int mrow0 = (MR == 64) ? ((sy & 1) << 6) : 0;
  const int nTot = nRec + nProj;

  if (MR == 64 && sy >= 2 * nTot) {
    // ---- weight-cast block (P0 only): WhR | WhU | Wc-pad, grid-stride ----
    const long TCB = (long)(gridDim.y - 2 * nTot) * 32;
    const long fc = (long)(sy - 2 * nTot) * 32 + blockIdx.x;
    const long Q = 1048576, total = 2 * Q + (long)kCP * kH / 4;
    const half4v z4h = {(_Float16)0, (_Float16)0, (_Float16)0, (_Float16)0};
    for (long i = fc * 256 + tid; i < total; i += TCB * 256) {
      if (i < Q) {
        WhRhD[i] = __builtin_convertvector(WhRf[i], half4v);
      } else if (i < 2 * Q) {
        WhUhD[i - Q] = __builtin_convertvector(WhUf[i - Q], half4v);
      } else {
        const long k = i - 2 * Q;
        WchD[k] = (k < (long)kC * kH / 4)
                      ? __builtin_convertvector(Wcf[k], half4v) : z4h;
      }
    }
    return;
  }

  f32x4 acc[FA][4];
  const f32x4 z4 = {0.f, 0.f, 0.f, 0.f};
#pragma unroll
  for (int a = 0; a < FA; ++a)
#pragma unroll
    for (int b = 0; b < 4; ++b) acc[a][b] = z4;

  // staging rows/offsets (LDS-local row; kk pre-swizzled k-offset)
  int srow[4], skk[4];
#pragma unroll
  for (int i = 0; i < 4; ++i) {
    srow[i] = i * 32 + (tid >> 3);
    skk[i] = ((tid & 7) ^ (srow[i] & 7)) * 8;
  }

  if (seg < nRec) {
    const bool isRoll = (u <= 16) && (seg == 0);
    const int c = (u <= 16) ? (seg - 1) : seg;
    const int pr = (u & 1) ^ 1, pw = u & 1;
    const int slot_in = isRoll ? (u - 2) : c;
    const int slot_out = isRoll ? (u - 1) : c;
    const half_t* A  = Hbuf + (size_t)pr * kPar + (size_t)slot_in * kSlot;
    const float* Cin = Cbuf + (size_t)pr * kPar + (size_t)slot_in * kSlot;
    half_t* Ho = Hbuf + (size_t)pw * kPar + (size_t)slot_out * kSlot;
    float*  Co = Cbuf + (size_t)pw * kPar + (size_t)slot_out * kSlot;
    const half_t* W  = isRoll ? Wr : Wu;
    const half_t* xi = isRoll ? (xiR + (size_t)(u - 1) * 524288)
                              : (xiU + (size_t)c * 524288);

    // T14 issue-early: Cin + xi into registers BEFORE the GEMM; their ~600cy
    // latency hides under the K-loop (first barrier drains vmcnt anyway).
    const int jg = j0 + (wc << 4) + row16;
    float cpre[FA][4];
    half4v xpre[FA][4];
#pragma unroll
    for (int a = 0; a < FA; ++a) {
      const int mb = mrow0 + wm * (MR / 2) + (a << 4) + (g << 2);
#pragma unroll
      for (int r = 0; r < 4; ++r) {
        const long idx = (long)(mb + r) * kH + jg;
        xpre[a][r] = *(const half4v*)&xi[idx * 4];
        cpre[a][r] = Cin[idx];
      }
    }

    long ao[FA], bo[4];
#pragma unroll
    for (int i = 0; i < FA; ++i) ao[i] = (long)(mrow0 + srow[i]) * kH + skk[i];
#pragma unroll
    for (int i = 0; i < 4; ++i) bo[i] = (long)brow_gate(srow[i], j0) * kH + skk[i];
    gemm_core<MR>(A, W, ao, bo, As, Bs, tid, wm, wc, row16, g, acc);

#pragma unroll
    for (int a = 0; a < FA; ++a) {
      const int mb = mrow0 + wm * (MR / 2) + (a << 4) + (g << 2);
#pragma unroll
      for (int r = 0; r < 4; ++r) {
        const int m = mb + r;
        const half4v xv = xpre[a][r];
        const float pi = acc[a][0][r] + (float)xv[0];
        const float pf = acc[a][1][r] + (float)xv[1];
        const float pg = acc[a][2][r] + (float)xv[2];
        const float po = acc[a][3][r] + (float)xv[3];
        const float cn = sgm(pf) * cpre[a][r] + sgm(pi) * ftanh(pg);
        const float hn = sgm(po) * ftanh(cn);
        Ho[(long)m * kH + jg] = (half_t)hn;
        Co[(long)m * kH + jg] = cn;
      }
    }
  } else {
    // ---- folded input-projection tile ----
    const int s = projStart + (seg - nRec);
    const int z = g_seq_z[s];
    const int rr = g_seq_r[s];
    const half_t* Wt = z ? WiUh : WiRh;
    const float* bias_p = z ? bup : brp;
    half_t* xi = z ? xiU : xiR;
    const int m0 = (rr << 7) + mrow0;

    long ao[FA], bo[4];
#pragma unroll
    for (int i = 0; i < FA; ++i) ao[i] = (long)(m0 + srow[i]) * kH + skk[i];
#pragma unroll
    for (int i = 0; i < 4; ++i) bo[i] = (long)brow_gate(srow[i], j0) * kH + skk[i];
    gemm_core<MR>(xh, Wt, ao, bo, As, Bs, tid, wm, wc, row16, g, acc);

    const int jg = j0 + (wc << 4) + row16;
    const f32x4 bv = *(const f32x4*)&bias_p[jg * 4];
#pragma unroll
    for (int a = 0; a < FA; ++a) {
      const int mb = m0 + wm * (MR / 2) + (a << 4) + (g << 2);
#pragma unroll
      for (int r4 = 0; r4 < 4; ++r4) {
        const float pi = acc[a][0][r4] + bv[0];
        const float pf = acc[a][1][r4] + bv[1];
        const float pg = acc[a][2][r4] + bv[2];
        const float po = acc[a][3][r4] + bv[3];
        half4v o;
        o[0] = (half_t)pi; o[1] = (half_t)pf; o[2] = (half_t)pg; o[3] = (half_t)po;
        *(half4v*)&xi[((long)(mb + r4) * kH + jg) * 4] = o;
        if (s == 0) {  // roll step 1 fold: c=0, h=0 -> slot 0 parity 1
          const float cn = sgm(pi) * ftanh(pg);
          const float hn = sgm(po) * ftanh(cn);
          Hbuf[(size_t)kPar + (long)(mb + r4) * kH + jg] = (half_t)hn;
          Cbuf[(size_t)kPar + (long)(mb + r4) * kH + jg] = cn;
        }
      }
    }
  }
}

// ---------------- classifier: half-tiles; A = parity-0 plane of Hbuf ---------
__global__ __launch_bounds__(256, 3) void cls_gemm(
    const half_t* __restrict__ Hfin, const half_t* __restrict__ Wcw,
    const float* __restrict__ bcp, float* __restrict__ out) {
  __shared__ __align__(16) half_t As[2 * 4096];
  __shared__ __align__(16) half_t Bs[2 * 8192];
  const int tid = threadIdx.x;
  const int lane = tid & 63;
  const int w = tid >> 6, wm = w >> 1, wc = w & 1;
  const int row16 = lane & 15;
  const int g = lane >> 4;
  const int n00 = blockIdx.x << 7;
  const int t = blockIdx.y >> 1;
  const int m0 = (t << 7) + ((blockIdx.y & 1) << 6);

  int srow[4], skk[4];
#pragma unroll
  for (int i = 0; i < 4; ++i) {
    srow[i] = i * 32 + (tid >> 3);
    skk[i] = ((tid & 7) ^ (srow[i] & 7)) * 8;
  }
  long ao[2], bo[4];
#pragma unroll
  for (int i = 0; i < 2; ++i) ao[i] = (long)(m0 + srow[i]) * kH + skk[i];
#pragma unroll
  for (int i = 0; i < 4; ++i) bo[i] = (long)(n00 + srow[i]) * kH + skk[i];

  f32x4 acc[2][4];
  const f32x4 z4 = {0.f, 0.f, 0.f, 0.f};
#pragma unroll
  for (int a = 0; a < 2; ++a)
#pragma unroll
    for (int b = 0; b < 4; ++b) acc[a][b] = z4;

  gemm_core<64>(Hfin, Wcw, ao, bo, As, Bs, tid, wm, wc, row16, g, acc);

#pragma unroll
  for (int a = 0; a < 2; ++a) {
    const int mb = m0 + wm * 32 + (a << 4) + (g << 2);
#pragma unroll
    for (int b = 0; b < 4; ++b) {
      const int n = n00 + (wc << 6) + (b << 4) + row16;
      if (n < kC) {
        const float bvv = bcp[n];
#pragma unroll
        for (int r = 0; r < 4; ++r) {
          const int m = mb + r;
          const int bi = m & 127;
          out[((long)bi * kT + t) * kC + n] = acc[a][b][r] + bvv;
        }
      }
    }
  }
}

extern "C" void kernel_launch(void* const* d_in, const int* in_sizes, int n_in,
                              void* d_out, int out_size, void* d_ws, size_t ws_size,
                              hipStream_t stream) {
  const float* x   = (const float*)d_in[0];
  const float* WiR = (const float*)d_in[1];
  const float* WhR = (const float*)d_in[2];
  const float* biR = (const float*)d_in[3];
  const float* bhR = (const float*)d_in[4];
  const float* WiU = (const float*)d_in[5];
  const float* WhU = (const float*)d_in[6];
  const float* biU = (const float*)d_in[7];
  const float* bhU = (const float*)d_in[8];
  const float* Wc  = (const float*)d_in[9];
  const float* bc  = (const float*)d_in[10];

  size_t off = 0;
  auto alloc = [&](size_t bytes) -> void* {
    void* p = (char*)d_ws + off;
    off += (bytes + 255) & ~(size_t)255;
    return p;
  };
  half_t* xh   = (half_t*)alloc((size_t)2048 * 1024 * 2);
  half_t* WiRh = (half_t*)alloc((size_t)4096 * 1024 * 2);
  half_t* WhRh = (half_t*)alloc((size_t)4096 * 1024 * 2);
  half_t* WiUh = (half_t*)alloc((size_t)4096 * 1024 * 2);
  half_t* WhUh = (half_t*)alloc((size_t)4096 * 1024 * 2);
  half_t* Wch  = (half_t*)alloc((size_t)2560 * 1024 * 2);
  float*  br   = (float*)alloc(4096 * 4);
  float*  bu   = (float*)alloc(4096 * 4);
  float*  bcp  = (float*)alloc(2560 * 4);
  half_t* xiR  = (half_t*)alloc((size_t)2048 * 4096 * 2);
  half_t* xiU  = (half_t*)alloc((size_t)2048 * 4096 * 2);
  half_t* Hbuf = (half_t*)alloc((size_t)2 * kPar * 2);
  float*  Cbuf = (float*)alloc((size_t)2 * kPar * 4);
  float*  outp = (float*)d_out;
  (void)ws_size; (void)in_sizes; (void)n_in; (void)out_size;

  // slim setup: x transpose + WiR/WiU casts + bias packs (one dispatch)
  setup_all<<<10256, 256, 0, stream>>>(
      (const flt4v*)WiR, (const flt4v*)WiU, x, biR, bhR, biU, bhU, bc,
      (half4v*)WiRh, (half4v*)WiUh, xh, br, bu, bcp);

  // P0: proj s=0..3 (xiR r0[+roll1 fold], r1; xiU r0; xiR r2) as 8 half-tiles
  // + 16 y of grid-stride cast blocks (WhR/WhU/Wc -> fp16; needed from u=2).
  pipe_step<64><<<dim3(32, 2 * 4 + 16), 256, 0, stream>>>(
      0, 0, 0, 4, xh, WiRh, WiUh, br, bu, WhRh, WhUh, xiR, xiU, Hbuf, Cbuf,
      (const flt4v*)WhR, (const flt4v*)WhU, (const flt4v*)Wc,
      (half4v*)WhRh, (half4v*)WhUh, (half4v*)Wch);

  // pipelined recurrences, u=2..18; remaining proj spread over the
  // latency-bound small steps (u=2..10) per g_seq schedule. Every xi row
  // lands >=1 dispatch before its first reader (verified row-by-row).
  static const int pjs[19] = {0,0, 4, 8, 12, 16, 19, 22, 25, 28, 30, 0,0,0,0,0,0,0,0};
  static const int pjn[19] = {0,0, 4, 4,  4,  3,  3,  3,  3,  2,  2, 0,0,0,0,0,0,0,0};
  for (int u = 2; u <= 18; ++u) {
    const int nchain = (u - 2 < 15 ? u - 2 : 15) + 1;
    const int nRec = (u <= 16 ? 1 : 0) + nchain;
    const int nProj = pjn[u];
    if (u <= 12) {
      pipe_step<64><<<dim3(32, 2 * (nRec + nProj)), 256, 0, stream>>>(
          u, nRec, pjs[u], nProj, xh, WiRh, WiUh, br, bu, WhRh, WhUh, xiR, xiU,
          Hbuf, Cbuf, (const flt4v*)WhR, (const flt4v*)WhU, (const flt4v*)Wc,
          (half4v*)WhRh, (half4v*)WhUh, (half4v*)Wch);
    } else {
      pipe_step<128><<<dim3(32, nRec), 256, 0, stream>>>(
          u, nRec, 0, 0, xh, WiRh, WiUh, br, bu, WhRh, WhUh, xiR, xiU,
          Hbuf, Cbuf, (const flt4v*)WhR, (const flt4v*)WhU, (const flt4v*)Wc,
          (half4v*)WhRh, (half4v*)WhUh, (half4v*)Wch);
    }
  }

  // classifier: finals are parity-0 slots 0..15; half-tiles (20 x 32 grid)
  cls_gemm<<<dim3(20, 32), 256, 0, stream>>>(Hbuf, Wch, bcp, (float*)outp);
}

// Round 12
// 422.743 us; speedup vs baseline: 1.3500x; 1.0058x over previous
//
#include <hip/hip_runtime.h>
#include <cstdint>

using half_t = _Float16;
using half8  = __attribute__((ext_vector_type(8))) _Float16;
using half4v = __attribute__((ext_vector_type(4))) _Float16;
using f32x4  = __attribute__((ext_vector_type(4))) float;
using flt4v  = __attribute__((ext_vector_type(4))) float;

namespace {
constexpr int kT = 16, kH = 1024, kFH = 4096, kC = 2513, kCP = 2560;
constexpr int kSlot = 128 * 1024;   // elements per state slot (128 rows x 1024)
constexpr int kPar  = 17 * kSlot;   // elements per parity plane
}

// proj sequence: global slot s -> (z, row). Front-shifted schedule: P0 takes
// s=0..7; steps u=2..10 take the rest. Every xi row lands >=1 dispatch before
// its first reader (xiR r first read at u=r+1 roll; xiU rc first read u=c+2).
__device__ __constant__ unsigned char g_seq_z[32] = {
    0,0,1,0, 0,0,1,1, 0,0,1,1, 0,0,1,1, 0,0,1, 0,0,1, 0,0,1, 0,1,1, 1,1, 1,1};
__device__ __constant__ unsigned char g_seq_r[32] = {
    0,1,0,2, 3,4,1,2, 5,6,3,4, 7,8,5,6, 9,10,7, 11,12,8, 13,14,9, 15,10,11, 12,13, 14,15};

__device__ __forceinline__ void gload16(const void* g, void* l) {
  __builtin_amdgcn_global_load_lds((const __attribute__((address_space(1))) void*)g,
                                   (__attribute__((address_space(3))) void*)l, 16, 0, 0);
}
// fast sigmoid / tanh: __expf + v_rcp. No clamp needed: exp(+inf)->inf,
// 1+inf=inf, rcp(inf)=0 -> tanh=+1 exactly; exp(-inf)->0 -> tanh=-1.
__device__ __forceinline__ float sgm(float x) {
  return __builtin_amdgcn_rcpf(1.0f + __expf(-x));
}
__device__ __forceinline__ float ftanh(float x) {
  return 1.0f - 2.0f * __builtin_amdgcn_rcpf(1.0f + __expf(2.0f * x));
}

// ---------------- slim setup: x transpose + WiR/WiU casts + bias packs -------
__global__ void setup_all(const flt4v* __restrict__ WiR, const flt4v* __restrict__ WiU,
                          const float* __restrict__ x,
                          const float* __restrict__ biR, const float* __restrict__ bhR,
                          const float* __restrict__ biU, const float* __restrict__ bhU,
                          const float* __restrict__ bc,
                          half4v* __restrict__ WiRh, half4v* __restrict__ WiUh,
                          half_t* __restrict__ xh,
                          float* __restrict__ br_p, float* __restrict__ bu_p,
                          float* __restrict__ bcp) {
  int blk = blockIdx.x;
  if (blk < 8192) {  // WiR/WiU casts
    long i = (long)blk * 256 + threadIdx.x;
    const long Q = 1048576;
    if (i < Q) { WiRh[i] = __builtin_convertvector(WiR[i], half4v); return; }
    i -= Q;
    WiUh[i] = __builtin_convertvector(WiU[i], half4v);
    return;
  }
  blk -= 8192;
  if (blk < 2048) {  // x transpose [B,T,F] -> [t*128+b][F], fp16
    int t = blk >> 7, b = blk & 127;
    const flt4v* src = (const flt4v*)(x + ((long)b * kT + t) * kH);
    half4v* dst = (half4v*)(xh + (long)blk * kH);
    dst[threadIdx.x] = __builtin_convertvector(src[threadIdx.x], half4v);
    return;
  }
  blk -= 2048;
  {  // bias packs: br_p/bu_p [j][gate]; bcp padded linear
    int i = blk * 256 + threadIdx.x;
    if (i < kFH) {
      int j = i >> 2, gt = i & 3;
      br_p[i] = biR[gt * kH + j] + bhR[gt * kH + j];
      bu_p[i] = biU[gt * kH + j] + bhU[gt * kH + j];
    }
    if (i < kCP) bcp[i] = (i < kC) ? bc[i] : 0.0f;
  }
}

// gate-interleaved B-row mapping: LDS B-row r -> weight row gate(r)*1024 + j0 + jj(r)
__device__ __forceinline__ int brow_gate(int r, int j0) {
  return (((r >> 4) & 3) << 10) + j0 + ((r >> 6) << 4) + (r & 15);
}

// ---------------- GEMM core: MR x 128 tile, K=1024, BK=64, dbuf + swizzle ----
// (round-3/7 proven core, templated on M rows: 128 = full, 64 = half-tile.)
// LDS per buffer: [MR rows][8 slots of 8 halfs]; slot s holds global k-chunk
// (s ^ (row&7)) -> ds_read_b128 2-way-conflict-free (free per m136).
template <int MR>
__device__ __forceinline__ void gemm_core(
    const half_t* __restrict__ A, const half_t* __restrict__ B,
    const long* ao, const long* bo, half_t* AsB, half_t* BsB,
    int tid, int wm, int wc, int row16, int g, f32x4 acc[][4]) {
  constexpr int UA = MR / 32;       // A stage iterations per thread
  constexpr int ABUF = MR * 64;     // halfs per A buffer
#pragma unroll
  for (int i = 0; i < UA; ++i) gload16(A + ao[i], AsB + (i * 256 + tid) * 8);
#pragma unroll
  for (int i = 0; i < 4; ++i) gload16(B + bo[i], BsB + (i * 256 + tid) * 8);
  __syncthreads();
  int p = 0;
  for (int kt = 64; kt <= 1024; kt += 64) {
    if (kt < 1024) {
      half_t* as_n = AsB + (p ^ 1) * ABUF;
      half_t* bs_n = BsB + (p ^ 1) * 8192;
#pragma unroll
      for (int i = 0; i < UA; ++i) gload16(A + ao[i] + kt, as_n + (i * 256 + tid) * 8);
#pragma unroll
      for (int i = 0; i < 4; ++i) gload16(B + bo[i] + kt, bs_n + (i * 256 + tid) * 8);
    }
    const half_t* as_ = AsB + p * ABUF;
    const half_t* bs_ = BsB + p * 8192;
#pragma unroll
    for (int s = 0; s < 2; ++s) {
      half8 af[UA], bf[4];
#pragma unroll
      for (int a = 0; a < UA; ++a) {
        const int row = wm * (MR / 2) + (a << 4) + row16;
        const int slot = (s * 4 + g) ^ (row & 7);
        af[a] = *(const half8*)&as_[row * 64 + slot * 8];
      }
#pragma unroll
      for (int b = 0; b < 4; ++b) {
        const int row = (wc << 6) + (b << 4) + row16;
        const int slot = (s * 4 + g) ^ (row & 7);
        bf[b] = *(const half8*)&bs_[row * 64 + slot * 8];
      }
#pragma unroll
      for (int a = 0; a < UA; ++a)
#pragma unroll
        for (int b = 0; b < 4; ++b)
          acc[a][b] = __builtin_amdgcn_mfma_f32_16x16x32_f16(af[a], bf[b], acc[a][b], 0, 0, 0);
    }
    __syncthreads();
    p ^= 1;
  }
}

// ---------------- pipelined recurrence step + folded proj/cast segments ------
// Global step u. MR=64: blockIdx.y = 2*seg + mhalf; MR=128: blockIdx.y = seg.
// seg < nRec: recurrence (roll if u<=16 && seg==0, else chain c). Chains read
// parity (u&1)^1, write u&1. Roll at u reads slot u-2, seeds slot u-1. Finals
// land in parity-0 slots 0..15 (= cls input).
// seg in [nRec, nRec+nProj): proj tile s = projStart + (seg-nRec), mapped via
// g_seq_z/r. s==0 ALSO computes roll step 1 (h0=c0=0) into slot 0 parity 1.
// blockIdx.y >= 2*(nRec+nProj) (P0 only): grid-stride weight-cast blocks for
// WhR/WhU/Wc (deferred from setup; first needed at u=2 / cls).
template <int MR>
__global__ __launch_bounds__(256, (MR == 64 ? 3 : 2)) void pipe_step(
    const int u, const int nRec, const int projStart, const int nProj,
    const half_t* __restrict__ xh,
    const half_t* __restrict__ WiRh, const half_t* __restrict__ WiUh,
    const float* __restrict__ brp, const float* __restrict__ bup,
    const half_t* __restrict__ Wr, const half_t* __restrict__ Wu,
    half_t* __restrict__ xiR, half_t* __restrict__ xiU,
    half_t* __restrict__ Hbuf, float* __restrict__ Cbuf,
    const flt4v* __restrict__ WhRf, const flt4v* __restrict__ WhUf,
    const flt4v* __restrict__ Wcf,
    half4v* __restrict__ WhRhD, half4v* __restrict__ WhUhD,
    half4v* __restrict__ WchD) {
  __shared__ __align__(16) half_t As[2 * MR * 64];
  __shared__ __align__(16) half_t Bs[2 * 8192];
  constexpr int FA = MR / 32;       // A fragments per wave
  const int tid = threadIdx.x;
  const int lane = tid & 63;
  const int w = tid >> 6, wm = w >> 1, wc = w & 1;
  const int row16 = lane & 15;
  const int g = lane >> 4;
  const int j0 = blockIdx.x << 5;   // j-tile; XCD = blockIdx.x%8 (32*y % 8 == 0)
  const int sy = blockIdx.y;
  const int seg = (MR == 64) ? (sy >> 1) : sy;
  const int mrow0 = (MR == 64) ? ((sy & 1) << 6) : 0;
  const int nTot = nRec + nProj;

  if (MR == 64 && sy >= 2 * nTot) {
    // ---- weight-cast block (P0 only): WhR | WhU | Wc-pad, grid-stride ----
    const long TCB = (long)(gridDim.y - 2 * nTot) * 32;
    const long fc = (long)(sy - 2 * nTot) * 32 + blockIdx.x;
    const long Q = 1048576, total = 2 * Q + (long)kCP * kH / 4;
    const half4v z4h = {(_Float16)0, (_Float16)0, (_Float16)0, (_Float16)0};
    for (long i = fc * 256 + tid; i < total; i += TCB * 256) {
      if (i < Q) {
        WhRhD[i] = __builtin_convertvector(WhRf[i], half4v);
      } else if (i < 2 * Q) {
        WhUhD[i - Q] = __builtin_convertvector(WhUf[i - Q], half4v);
      } else {
        const long k = i - 2 * Q;
        WchD[k] = (k < (long)kC * kH / 4)
                      ? __builtin_convertvector(Wcf[k], half4v) : z4h;
      }
    }
    return;
  }

  f32x4 acc[FA][4];
  const f32x4 z4 = {0.f, 0.f, 0.f, 0.f};
#pragma unroll
  for (int a = 0; a < FA; ++a)
#pragma unroll
    for (int b = 0; b < 4; ++b) acc[a][b] = z4;

  // staging rows/offsets (LDS-local row; kk pre-swizzled k-offset)
  int srow[4], skk[4];
#pragma unroll
  for (int i = 0; i < 4; ++i) {
    srow[i] = i * 32 + (tid >> 3);
    skk[i] = ((tid & 7) ^ (srow[i] & 7)) * 8;
  }

  if (seg < nRec) {
    const bool isRoll = (u <= 16) && (seg == 0);
    const int c = (u <= 16) ? (seg - 1) : seg;
    const int pr = (u & 1) ^ 1, pw = u & 1;
    const int slot_in = isRoll ? (u - 2) : c;
    const int slot_out = isRoll ? (u - 1) : c;
    const half_t* A  = Hbuf + (size_t)pr * kPar + (size_t)slot_in * kSlot;
    const float* Cin = Cbuf + (size_t)pr * kPar + (size_t)slot_in * kSlot;
    half_t* Ho = Hbuf + (size_t)pw * kPar + (size_t)slot_out * kSlot;
    float*  Co = Cbuf + (size_t)pw * kPar + (size_t)slot_out * kSlot;
    const half_t* W  = isRoll ? Wr : Wu;
    const half_t* xi = isRoll ? (xiR + (size_t)(u - 1) * 524288)
                              : (xiU + (size_t)c * 524288);

    // T14 issue-early: Cin + xi into registers BEFORE the GEMM; their ~600cy
    // latency hides under the K-loop (first barrier drains vmcnt anyway).
    const int jg = j0 + (wc << 4) + row16;
    float cpre[FA][4];
    half4v xpre[FA][4];
#pragma unroll
    for (int a = 0; a < FA; ++a) {
      const int mb = mrow0 + wm * (MR / 2) + (a << 4) + (g << 2);
#pragma unroll
      for (int r = 0; r < 4; ++r) {
        const long idx = (long)(mb + r) * kH + jg;
        xpre[a][r] = *(const half4v*)&xi[idx * 4];
        cpre[a][r] = Cin[idx];
      }
    }

    long ao[FA], bo[4];
#pragma unroll
    for (int i = 0; i < FA; ++i) ao[i] = (long)(mrow0 + srow[i]) * kH + skk[i];
#pragma unroll
    for (int i = 0; i < 4; ++i) bo[i] = (long)brow_gate(srow[i], j0) * kH + skk[i];
    gemm_core<MR>(A, W, ao, bo, As, Bs, tid, wm, wc, row16, g, acc);

#pragma unroll
    for (int a = 0; a < FA; ++a) {
      const int mb = mrow0 + wm * (MR / 2) + (a << 4) + (g << 2);
#pragma unroll
      for (int r = 0; r < 4; ++r) {
        const int m = mb + r;
        const half4v xv = xpre[a][r];
        const float pi = acc[a][0][r] + (float)xv[0];
        const float pf = acc[a][1][r] + (float)xv[1];
        const float pg = acc[a][2][r] + (float)xv[2];
        const float po = acc[a][3][r] + (float)xv[3];
        const float cn = sgm(pf) * cpre[a][r] + sgm(pi) * ftanh(pg);
        const float hn = sgm(po) * ftanh(cn);
        Ho[(long)m * kH + jg] = (half_t)hn;
        Co[(long)m * kH + jg] = cn;
      }
    }
  } else {
    // ---- folded input-projection tile ----
    const int s = projStart + (seg - nRec);
    const int z = g_seq_z[s];
    const int rr = g_seq_r[s];
    const half_t* Wt = z ? WiUh : WiRh;
    const float* bias_p = z ? bup : brp;
    half_t* xi = z ? xiU : xiR;
    const int m0 = (rr << 7) + mrow0;

    // T14 issue-early: bias vector before the GEMM
    const int jg = j0 + (wc << 4) + row16;
    const f32x4 bv = *(const f32x4*)&bias_p[jg * 4];

    long ao[FA], bo[4];
#pragma unroll
    for (int i = 0; i < FA; ++i) ao[i] = (long)(m0 + srow[i]) * kH + skk[i];
#pragma unroll
    for (int i = 0; i < 4; ++i) bo[i] = (long)brow_gate(srow[i], j0) * kH + skk[i];
    gemm_core<MR>(xh, Wt, ao, bo, As, Bs, tid, wm, wc, row16, g, acc);

#pragma unroll
    for (int a = 0; a < FA; ++a) {
      const int mb = m0 + wm * (MR / 2) + (a << 4) + (g << 2);
#pragma unroll
      for (int r4 = 0; r4 < 4; ++r4) {
        const float pi = acc[a][0][r4] + bv[0];
        const float pf = acc[a][1][r4] + bv[1];
        const float pg = acc[a][2][r4] + bv[2];
        const float po = acc[a][3][r4] + bv[3];
        half4v o;
        o[0] = (half_t)pi; o[1] = (half_t)pf; o[2] = (half_t)pg; o[3] = (half_t)po;
        *(half4v*)&xi[((long)(mb + r4) * kH + jg) * 4] = o;
        if (s == 0) {  // roll step 1 fold: c=0, h=0 -> slot 0 parity 1
          const float cn = sgm(pi) * ftanh(pg);
          const float hn = sgm(po) * ftanh(cn);
          Hbuf[(size_t)kPar + (long)(mb + r4) * kH + jg] = (half_t)hn;
          Cbuf[(size_t)kPar + (long)(mb + r4) * kH + jg] = cn;
        }
      }
    }
  }
}

// ---------------- classifier: half-tiles; A = parity-0 plane of Hbuf ---------
__global__ __launch_bounds__(256, 3) void cls_gemm(
    const half_t* __restrict__ Hfin, const half_t* __restrict__ Wcw,
    const float* __restrict__ bcp, float* __restrict__ out) {
  __shared__ __align__(16) half_t As[2 * 4096];
  __shared__ __align__(16) half_t Bs[2 * 8192];
  const int tid = threadIdx.x;
  const int lane = tid & 63;
  const int w = tid >> 6, wm = w >> 1, wc = w & 1;
  const int row16 = lane & 15;
  const int g = lane >> 4;
  const int n00 = blockIdx.x << 7;
  const int t = blockIdx.y >> 1;
  const int m0 = (t << 7) + ((blockIdx.y & 1) << 6);

  // T14 issue-early: bias scalars before the GEMM
  float bpre[4];
#pragma unroll
  for (int b = 0; b < 4; ++b)
    bpre[b] = bcp[n00 + (wc << 6) + (b << 4) + row16];

  int srow[4], skk[4];
#pragma unroll
  for (int i = 0; i < 4; ++i) {
    srow[i] = i * 32 + (tid >> 3);
    skk[i] = ((tid & 7) ^ (srow[i] & 7)) * 8;
  }
  long ao[2], bo[4];
#pragma unroll
  for (int i = 0; i < 2; ++i) ao[i] = (long)(m0 + srow[i]) * kH + skk[i];
#pragma unroll
  for (int i = 0; i < 4; ++i) bo[i] = (long)(n00 + srow[i]) * kH + skk[i];

  f32x4 acc[2][4];
  const f32x4 z4 = {0.f, 0.f, 0.f, 0.f};
#pragma unroll
  for (int a = 0; a < 2; ++a)
#pragma unroll
    for (int b = 0; b < 4; ++b) acc[a][b] = z4;

  gemm_core<64>(Hfin, Wcw, ao, bo, As, Bs, tid, wm, wc, row16, g, acc);

#pragma unroll
  for (int a = 0; a < 2; ++a) {
    const int mb = m0 + wm * 32 + (a << 4) + (g << 2);
#pragma unroll
    for (int b = 0; b < 4; ++b) {
      const int n = n00 + (wc << 6) + (b << 4) + row16;
      if (n < kC) {
#pragma unroll
        for (int r = 0; r < 4; ++r) {
          const int m = mb + r;
          const int bi = m & 127;
          out[((long)bi * kT + t) * kC + n] = acc[a][b][r] + bpre[b];
        }
      }
    }
  }
}

extern "C" void kernel_launch(void* const* d_in, const int* in_sizes, int n_in,
                              void* d_out, int out_size, void* d_ws, size_t ws_size,
                              hipStream_t stream) {
  const float* x   = (const float*)d_in[0];
  const float* WiR = (const float*)d_in[1];
  const float* WhR = (const float*)d_in[2];
  const float* biR = (const float*)d_in[3];
  const float* bhR = (const float*)d_in[4];
  const float* WiU = (const float*)d_in[5];
  const float* WhU = (const float*)d_in[6];
  const float* biU = (const float*)d_in[7];
  const float* bhU = (const float*)d_in[8];
  const float* Wc  = (const float*)d_in[9];
  const float* bc  = (const float*)d_in[10];

  size_t off = 0;
  auto alloc = [&](size_t bytes) -> void* {
    void* p = (char*)d_ws + off;
    off += (bytes + 255) & ~(size_t)255;
    return p;
  };
  half_t* xh   = (half_t*)alloc((size_t)2048 * 1024 * 2);
  half_t* WiRh = (half_t*)alloc((size_t)4096 * 1024 * 2);
  half_t* WhRh = (half_t*)alloc((size_t)4096 * 1024 * 2);
  half_t* WiUh = (half_t*)alloc((size_t)4096 * 1024 * 2);
  half_t* WhUh = (half_t*)alloc((size_t)4096 * 1024 * 2);
  half_t* Wch  = (half_t*)alloc((size_t)2560 * 1024 * 2);
  float*  br   = (float*)alloc(4096 * 4);
  float*  bu   = (float*)alloc(4096 * 4);
  float*  bcp  = (float*)alloc(2560 * 4);
  half_t* xiR  = (half_t*)alloc((size_t)2048 * 4096 * 2);
  half_t* xiU  = (half_t*)alloc((size_t)2048 * 4096 * 2);
  half_t* Hbuf = (half_t*)alloc((size_t)2 * kPar * 2);
  float*  Cbuf = (float*)alloc((size_t)2 * kPar * 4);
  float*  outp = (float*)d_out;
  (void)ws_size; (void)in_sizes; (void)n_in; (void)out_size;

  // slim setup: x transpose + WiR/WiU casts + bias packs (one dispatch)
  setup_all<<<10256, 256, 0, stream>>>(
      (const flt4v*)WiR, (const flt4v*)WiU, x, biR, bhR, biU, bhU, bc,
      (half4v*)WiRh, (half4v*)WiUh, xh, br, bu, bcp);

  // P0: proj s=0..7 (16 half-tiles; s=0 also folds roll step 1) + 8 y of
  // grid-stride cast blocks (WhR/WhU/Wc -> fp16). Grid = 768 = 3/CU capacity.
  pipe_step<64><<<dim3(32, 2 * 8 + 8), 256, 0, stream>>>(
      0, 0, 0, 8, xh, WiRh, WiUh, br, bu, WhRh, WhUh, xiR, xiU, Hbuf, Cbuf,
      (const flt4v*)WhR, (const flt4v*)WhU, (const flt4v*)Wc,
      (half4v*)WhRh, (half4v*)WhUh, (half4v*)Wch);

  // pipelined recurrences, u=2..18; remaining 24 proj tiles spread over the
  // latency-bound small steps (u=2..10). Front-shifted vs r10: small-u grids
  // are far below capacity so proj rides free; every xi row still lands >=1
  // dispatch before its first reader (verified row-by-row).
  static const int pjs[19] = {0,0, 8, 11, 14, 17, 20, 23, 26, 29, 31, 0,0,0,0,0,0,0,0};
  static const int pjn[19] = {0,0, 3,  3,  3,  3,  3,  3,  3,  2,  1, 0,0,0,0,0,0,0,0};
  for (int u = 2; u <= 18; ++u) {
    const int nchain = (u - 2 < 15 ? u - 2 : 15) + 1;
    const int nRec = (u <= 16 ? 1 : 0) + nchain;
    const int nProj = pjn[u];
    if (u <= 12) {
      pipe_step<64><<<dim3(32, 2 * (nRec + nProj)), 256, 0, stream>>>(
          u, nRec, pjs[u], nProj, xh, WiRh, WiUh, br, bu, WhRh, WhUh, xiR, xiU,
          Hbuf, Cbuf, (const flt4v*)WhR, (const flt4v*)WhU, (const flt4v*)Wc,
          (half4v*)WhRh, (half4v*)WhUh, (half4v*)Wch);
    } else {
      pipe_step<128><<<dim3(32, nRec), 256, 0, stream>>>(
          u, nRec, 0, 0, xh, WiRh, WiUh, br, bu, WhRh, WhUh, xiR, xiU,
          Hbuf, Cbuf, (const flt4v*)WhR, (const flt4v*)WhU, (const flt4v*)Wc,
          (half4v*)WhRh, (half4v*)WhUh, (half4v*)Wch);
    }
  }

  // classifier: finals are parity-0 slots 0..15; half-tiles (20 x 32 grid)
  cls_gemm<<<dim3(20, 32), 256, 0, stream>>>(Hbuf, Wch, bcp, (float*)outp);
}